// Round 14
// baseline (870.397 us; speedup 1.0000x reference)
//
#include <hip/hip_runtime.h>
#include <cstdint>

__device__ __forceinline__ float clamp01f(float v) { return fminf(fmaxf(v, 0.0f), 1.0f); }

// factored trilinear basis: 12 mults for the 8 corner weights
__device__ __forceinline__ void basis8(float p0, float p1, float p2, float* bs)
{
    float q0 = 1.f - p0, q1 = 1.f - p1, q2 = 1.f - p2;
    float t00 = q0 * q1, t10 = p0 * q1, t01 = q0 * p1, t11 = p0 * p1;
    bs[0] = t00 * q2; bs[1] = t10 * q2; bs[2] = t01 * q2; bs[3] = t11 * q2;
    bs[4] = t00 * p2; bs[5] = t10 * p2; bs[6] = t01 * p2; bs[7] = t11 * p2;
}

// ======================= legacy CSR build (layers 3-5, small E) =======================
__global__ __launch_bounds__(256) void edge_count_kernel(
    const int* __restrict__ edst, int* __restrict__ cnt, int E)
{
    int e = blockIdx.x * 256 + threadIdx.x;
    if (e < E) atomicAdd(&cnt[__builtin_nontemporal_load(&edst[e])], 1);
}

__global__ __launch_bounds__(256) void edge_scatter_kernel(
    const int* __restrict__ esrc, const int* __restrict__ edst,
    int* __restrict__ off, int* __restrict__ srcs, int E, int rv)
{
    const int lo = (int)(blockIdx.x & 7) * rv;
    const int hi = lo + rv;
    const int base = (int)(blockIdx.x >> 3) << 10;
#pragma unroll
    for (int k = 0; k < 4; ++k) {
        int e = base + (k << 8) + threadIdx.x;
        if (e < E) {
            int d = __builtin_nontemporal_load(&edst[e]);
            if (d >= lo && d < hi) {
                int s = __builtin_nontemporal_load(&esrc[e]);
                int slot = atomicAdd(&off[d], 1);
                srcs[slot] = s;
            }
        }
    }
}

// ============== hierarchical exclusive scan ==============
__global__ __launch_bounds__(256) void scan1_kernel(
    const int* __restrict__ cnt, int* __restrict__ off, int* __restrict__ bsum, int V)
{
    __shared__ int lds[4096];
    __shared__ int ssum[256];
    const int t = threadIdx.x;
    const int base = blockIdx.x * 4096;
    for (int i = t; i < 4096; i += 256) {
        int g = base + i;
        lds[i] = (g < V) ? cnt[g] : 0;
    }
    __syncthreads();
    int loc[16];
    int s = 0;
#pragma unroll
    for (int k = 0; k < 16; ++k) { loc[k] = s; s += lds[t * 16 + k]; }
    ssum[t] = s;
    __syncthreads();
    for (int d = 1; d < 256; d <<= 1) {
        int v = (t >= d) ? ssum[t - d] : 0;
        __syncthreads();
        ssum[t] += v;
        __syncthreads();
    }
    const int tbase = (t == 0) ? 0 : ssum[t - 1];
    if (t == 255 && bsum) bsum[blockIdx.x] = ssum[255];
#pragma unroll
    for (int k = 0; k < 16; ++k) lds[t * 16 + k] = tbase + loc[k];
    __syncthreads();
    for (int i = t; i < 4096; i += 256) {
        int g = base + i;
        if (g < V) off[g] = lds[i];
    }
}

__global__ __launch_bounds__(256) void scan_add_kernel(
    int* __restrict__ off, const int* __restrict__ bso, int V)
{
    int g = blockIdx.x * 256 + threadIdx.x;
    if (g < V) off[g] += bso[g >> 12];
}

// ======================= bucketed CSR build (L1, L2) =======================
__global__ __launch_bounds__(256) void bin_count_kernel(
    const int* __restrict__ edst, int* __restrict__ gcnt, int E, int shift)
{
    __shared__ int h[256];
    const int t = threadIdx.x;
    h[t] = 0;
    __syncthreads();
    const int base = blockIdx.x << 12;
#pragma unroll
    for (int k = 0; k < 16; ++k) {
        int e = base + (k << 8) + t;
        if (e < E) {
            int d = __builtin_nontemporal_load(&edst[e]);
            atomicAdd(&h[d >> shift], 1);
        }
    }
    __syncthreads();
    if (h[t]) atomicAdd(&gcnt[t], h[t]);
}

// staging packed as int2 (dst, src): one 8B store per edge, paired locality on read.
__global__ __launch_bounds__(256) void bin_scatter_kernel(
    const int* __restrict__ esrc, const int* __restrict__ edst,
    int* __restrict__ gcur, int2* __restrict__ st, int E, int shift)
{
    __shared__ int d_l[4096];
    __shared__ int s_l[4096];
    __shared__ int h[256];
    __shared__ int rbase[256];
    const int t = threadIdx.x;
    h[t] = 0;
    __syncthreads();
    const int base = blockIdx.x << 12;
#pragma unroll
    for (int k = 0; k < 16; ++k) {
        int i = (k << 8) + t;
        int e = base + i;
        if (e < E) {
            int d = __builtin_nontemporal_load(&edst[e]);
            int s = __builtin_nontemporal_load(&esrc[e]);
            d_l[i] = d; s_l[i] = s;
            atomicAdd(&h[d >> shift], 1);
        }
    }
    __syncthreads();
    rbase[t] = h[t] ? atomicAdd(&gcur[t], h[t]) : 0;
    h[t] = 0;   // reuse as cursor
    __syncthreads();
#pragma unroll
    for (int k = 0; k < 16; ++k) {
        int i = (k << 8) + t;
        int e = base + i;
        if (e < E) {
            int d = d_l[i];
            int b = d >> shift;
            int r = atomicAdd(&h[b], 1);
            st[rbase[b] + r] = make_int2(d, s_l[i]);
        }
    }
}

__global__ __launch_bounds__(1024) void bucket_csr_kernel(
    const int* __restrict__ gcur, const int* __restrict__ gcnt,
    const int2* __restrict__ st,
    int* __restrict__ cnt, int* __restrict__ off, int* __restrict__ srcs,
    int V, int shift)
{
    __shared__ int h[2048];
    __shared__ int o[2048];
    __shared__ int ps[1024];
    const int t = threadIdx.x;
    const int b = blockIdx.x;
    const int v0 = b << shift;
    const int nv = min(1 << shift, V - v0);
    const int s1 = gcur[b];
    const int s0 = s1 - gcnt[b];
    h[t] = 0; h[t + 1024] = 0;
    __syncthreads();
    for (int i = s0 + t; i < s1; i += 1024)
        atomicAdd(&h[st[i].x - v0], 1);
    __syncthreads();
    int a = h[2 * t], b2 = h[2 * t + 1];
    ps[t] = a + b2;
    __syncthreads();
    for (int d = 1; d < 1024; d <<= 1) {
        int v = (t >= d) ? ps[t - d] : 0;
        __syncthreads();
        ps[t] += v;
        __syncthreads();
    }
    int pb = (t == 0) ? 0 : ps[t - 1];
    o[2 * t] = pb;
    o[2 * t + 1] = pb + a;
    __syncthreads();
    for (int i = t; i < nv; i += 1024) {
        int hv = h[i];
        cnt[v0 + i] = hv;
        off[v0 + i] = s0 + o[i] + hv;   // segment END convention
    }
    __syncthreads();
    for (int i = s0 + t; i < s1; i += 1024) {
        int2 e = st[i];
        int r = atomicAdd(&o[e.x - v0], 1);
        srcs[s0 + r] = e.y;
    }
}

// ======================= pack (x, pos) into float4 for layer-1 gathers =======
__global__ __launch_bounds__(256) void pack_xpos_kernel(
    const float* __restrict__ x, const float* __restrict__ pos,
    float4* __restrict__ xp, int V)
{
    int n = blockIdx.x * 256 + threadIdx.x;
    if (n >= V) return;
    xp[n] = make_float4(x[n], pos[n * 3 + 0], pos[n * 3 + 1], pos[n * 3 + 2]);
}

// ========== Layer-1 fused, tsum, DENSE output; 4-edge unrolled gather ==========
__device__ __forceinline__ void l1_edge_acc(
    const float4 d, const float4 a, float inv2mv, float ts[8][3])
{
    float p0 = clamp01f((d.y - a.y) * inv2mv + 0.5f);
    float p1 = clamp01f((d.z - a.z) * inv2mv + 0.5f);
    float p2 = clamp01f((d.w - a.w) * inv2mv + 0.5f);
    float bs[8];
    basis8(p0, p1, p2, bs);
#pragma unroll
    for (int s8 = 0; s8 < 8; ++s8) {
        ts[s8][0] += bs[s8] * a.x;
        ts[s8][1] += bs[s8] * a.y;
        ts[s8][2] += bs[s8] * a.z;
    }
}

__global__ __launch_bounds__(256) void l1_fused_kernel(
    const int* __restrict__ off, const int* __restrict__ cnt, const int* __restrict__ srcs,
    const float4* __restrict__ xp,
    const float* __restrict__ Wk, const float* __restrict__ Wr,
    const float* __restrict__ bias, float* __restrict__ out,
    float inv2mv, int V)
{
    __shared__ float sWk[384];
    __shared__ float sWr[48];
    __shared__ float sB[16];
    const int t = threadIdx.x;
    for (int i = t; i < 384; i += 256) sWk[i] = Wk[i];
    if (t < 48) sWr[t] = Wr[t];
    if (t < 16) sB[t] = bias[t];
    __syncthreads();
    const int v = blockIdx.x * 256 + t;
    if (v >= V) return;
    const float4 d = xp[v];  // x, px, py, pt
    const int e1 = off[v];
    const int n = cnt[v];
    float ts[8][3];
#pragma unroll
    for (int s8 = 0; s8 < 8; ++s8) { ts[s8][0] = 0.f; ts[s8][1] = 0.f; ts[s8][2] = 0.f; }
    int j = e1 - n;
    for (; j + 3 < e1; j += 4) {
        float4 a0 = xp[srcs[j]];
        float4 a1 = xp[srcs[j + 1]];
        float4 a2 = xp[srcs[j + 2]];
        float4 a3 = xp[srcs[j + 3]];
        l1_edge_acc(d, a0, inv2mv, ts);
        l1_edge_acc(d, a1, inv2mv, ts);
        l1_edge_acc(d, a2, inv2mv, ts);
        l1_edge_acc(d, a3, inv2mv, ts);
    }
    for (; j < e1; ++j)
        l1_edge_acc(d, xp[srcs[j]], inv2mv, ts);
    const float invn = 1.0f / fmaxf((float)n, 1.0f);
    float rr[16];
#pragma unroll
    for (int c = 0; c < 16; ++c) {
        float m = 0.f;
#pragma unroll
        for (int s8 = 0; s8 < 8; ++s8)
            m += ts[s8][0] * sWk[s8 * 48 + c]
               + ts[s8][1] * sWk[s8 * 48 + 16 + c]
               + ts[s8][2] * sWk[s8 * 48 + 32 + c];
        float r = m * invn + d.x * sWr[c] + d.y * sWr[16 + c] + d.z * sWr[32 + c] + sB[c];
        rr[c] = fmaxf(r, 0.0f);
    }
    float4* op = (float4*)(out + (size_t)v * 16);
#pragma unroll
    for (int k = 0; k < 4; ++k)
        op[k] = make_float4(rr[4 * k], rr[4 * k + 1], rr[4 * k + 2], rr[4 * k + 3]);
}

// ========== Layer-2 tsum, quarter-wave-per-node, LDS-staged weights ==========
__device__ __forceinline__ void l2_edge_acc(
    const float4 pd, const float4 pa, float fa, int l16, float inv2mv,
    float* accF, float* accP)
{
    float p0 = clamp01f((pd.x - pa.x) * inv2mv + 0.5f);
    float p1 = clamp01f((pd.y - pa.y) * inv2mv + 0.5f);
    float p2 = clamp01f((pd.z - pa.z) * inv2mv + 0.5f);
    float bs[8];
    basis8(p0, p1, p2, bs);
    const float fp = (l16 == 0) ? pa.x : ((l16 == 1) ? pa.y : 0.f);
#pragma unroll
    for (int s8 = 0; s8 < 8; ++s8) {
        accF[s8] += bs[s8] * fa;
        accP[s8] += bs[s8] * fp;
    }
}

template<int NW>
__global__ __launch_bounds__(64 * NW) void tsum16_layer_kernel(
    const int* __restrict__ off, const int* __restrict__ cnt, const int* __restrict__ srcs,
    const float4* __restrict__ pos4, const float* __restrict__ feat,
    const float* __restrict__ Wk, const float* __restrict__ Wr,
    const float* __restrict__ bias, float* __restrict__ out,
    float inv2mv, int V)
{
    __shared__ float sW[8 * 18 * 64];   // 9216 floats: all Wk slices
    __shared__ float sR[18 * 64];       // Wr
    __shared__ float sB2[64];
    __shared__ float tsum[NW][4][18][9];
    const int tid = threadIdx.x;
    const int w = tid >> 6, lane = tid & 63;
    const int q = lane >> 4, l16 = lane & 15;
    const int vbase = (blockIdx.x * NW + w) * 4;
    const int v = vbase + q;        // V divisible by 4*NW -> always < V

    // weight preload overlaps gather (no dependency until the barrier)
    for (int i = tid; i < 9216; i += 64 * NW) sW[i] = Wk[i];
    for (int i = tid; i < 1152; i += 64 * NW) sR[i] = Wr[i];
    if (tid < 64) sB2[tid] = bias[tid];

    const float4 pd = pos4[v];
    const int e1 = off[v];
    const int n = cnt[v];
    float accF[8], accP[8];
#pragma unroll
    for (int s8 = 0; s8 < 8; ++s8) { accF[s8] = 0.f; accP[s8] = 0.f; }
    int j = e1 - n;
    for (; j + 3 < e1; j += 4) {
        const int s0 = srcs[j], s1 = srcs[j + 1], s2 = srcs[j + 2], s3 = srcs[j + 3];
        const float4 pa = pos4[s0];
        const float4 pb = pos4[s1];
        const float4 pc = pos4[s2];
        const float4 pe = pos4[s3];
        const float fa = feat[s0 * 16 + l16];
        const float fb = feat[s1 * 16 + l16];
        const float fc = feat[s2 * 16 + l16];
        const float fe = feat[s3 * 16 + l16];
        l2_edge_acc(pd, pa, fa, l16, inv2mv, accF, accP);
        l2_edge_acc(pd, pb, fb, l16, inv2mv, accF, accP);
        l2_edge_acc(pd, pc, fc, l16, inv2mv, accF, accP);
        l2_edge_acc(pd, pe, fe, l16, inv2mv, accF, accP);
    }
    for (; j < e1; ++j) {
        const int s = srcs[j];
        const float4 pa = pos4[s];
        const float fa = feat[s * 16 + l16];
        l2_edge_acc(pd, pa, fa, l16, inv2mv, accF, accP);
    }
#pragma unroll
    for (int s8 = 0; s8 < 8; ++s8)
        tsum[w][q][l16][s8] = accF[s8];
    tsum[w][q][l16][8] = feat[v * 16 + l16];
    if (l16 < 2) {
#pragma unroll
        for (int s8 = 0; s8 < 8; ++s8)
            tsum[w][q][16 + l16][s8] = accP[s8];
        tsum[w][q][16 + l16][8] = (l16 == 0) ? pd.x : pd.y;
    }
    __syncthreads();

    float oA[4], oR[4];
#pragma unroll
    for (int b = 0; b < 4; ++b) { oA[b] = 0.f; oR[b] = 0.f; }
    for (int s8 = 0; s8 < 8; ++s8) {
        const float* W = sW + s8 * (18 * 64);
        for (int ci = 0; ci < 18; ++ci) {
            float wv = W[ci * 64 + lane];
#pragma unroll
            for (int b = 0; b < 4; ++b)
                oA[b] += tsum[w][b][ci][s8] * wv;
        }
    }
    for (int ci = 0; ci < 18; ++ci) {
        float wv = sR[ci * 64 + lane];
#pragma unroll
        for (int b = 0; b < 4; ++b)
            oR[b] += tsum[w][b][ci][8] * wv;
    }
    const float bi = sB2[lane];
#pragma unroll
    for (int b = 0; b < 4; ++b) {
        int vv = vbase + b;
        float invn = 1.0f / fmaxf((float)cnt[vv], 1.0f);
        out[(size_t)vv * 64 + lane] = fmaxf(oA[b] * invn + oR[b] + bi, 0.0f);
    }
}

// ========== Generic tsum layer (L3-5), 2-edge unroll, factored basis, fused pooling ==
// PMODE: 0 = dense out only (L5), 1 = atomic max-pool only (L3),
//        2 = dense out + atomic mean-pool sums (L4).
template<int CINF, int COUT, int NV, int NW, int PMODE>
__global__ __launch_bounds__(64 * NW) void tsum_layer_kernel(
    const int* __restrict__ off, const int* __restrict__ cnt, const int* __restrict__ srcs,
    const float4* __restrict__ pos4, const float* __restrict__ feat,
    const float* __restrict__ Wk, const float* __restrict__ Wr,
    const float* __restrict__ bias, float* __restrict__ out,
    float* __restrict__ hp, float* __restrict__ psum, float* __restrict__ pcnt,
    float inv2mv, int V, int gx, int gy, int gt, int bdiv)
{
    constexpr int CIN = CINF + 2;
    constexpr int NCI = (CIN + 63) / 64;
    constexpr int NCC = COUT / 64;
    __shared__ float tsum[NW][NV][CIN][9];
    __shared__ int scl[NW][NV];
    const int tid = threadIdx.x;
    const int w = tid >> 6, lane = tid & 63;
    const int vbase = (blockIdx.x * NW + w) * NV;

    for (int b = 0; b < NV; ++b) {
        const int v = vbase + b;
        if (v >= V) break;
        const float4 pd = pos4[v];
        float acc[NCI][8];
#pragma unroll
        for (int k = 0; k < NCI; ++k)
#pragma unroll
            for (int s8 = 0; s8 < 8; ++s8) acc[k][s8] = 0.f;
        const int e1 = off[v];
        int j = e1 - cnt[v];
        for (; j + 1 < e1; j += 2) {
            const int s0 = srcs[j], s1 = srcs[j + 1];
            const float4 pa = pos4[s0];
            const float4 pb = pos4[s1];
            float fa[NCI], fb[NCI];
#pragma unroll
            for (int k = 0; k < NCI; ++k) {
                int ci = lane + 64 * k;
                fa[k] = (ci < CINF) ? feat[s0 * CINF + ci]
                       : (ci == CINF ? pa.x : (ci == CINF + 1 ? pa.y : 0.f));
                fb[k] = (ci < CINF) ? feat[s1 * CINF + ci]
                       : (ci == CINF ? pb.x : (ci == CINF + 1 ? pb.y : 0.f));
            }
            float pa0 = clamp01f((pd.x - pa.x) * inv2mv + 0.5f);
            float pa1 = clamp01f((pd.y - pa.y) * inv2mv + 0.5f);
            float pa2 = clamp01f((pd.z - pa.z) * inv2mv + 0.5f);
            float pb0 = clamp01f((pd.x - pb.x) * inv2mv + 0.5f);
            float pb1 = clamp01f((pd.y - pb.y) * inv2mv + 0.5f);
            float pb2 = clamp01f((pd.z - pb.z) * inv2mv + 0.5f);
            float ba[8], bb[8];
            basis8(pa0, pa1, pa2, ba);
            basis8(pb0, pb1, pb2, bb);
#pragma unroll
            for (int s8 = 0; s8 < 8; ++s8)
#pragma unroll
                for (int k = 0; k < NCI; ++k)
                    acc[k][s8] += ba[s8] * fa[k] + bb[s8] * fb[k];
        }
        if (j < e1) {
            const int s = srcs[j];
            const float4 pa = pos4[s];
            float fa[NCI];
#pragma unroll
            for (int k = 0; k < NCI; ++k) {
                int ci = lane + 64 * k;
                fa[k] = (ci < CINF) ? feat[s * CINF + ci]
                       : (ci == CINF ? pa.x : (ci == CINF + 1 ? pa.y : 0.f));
            }
            float p0 = clamp01f((pd.x - pa.x) * inv2mv + 0.5f);
            float p1 = clamp01f((pd.y - pa.y) * inv2mv + 0.5f);
            float p2 = clamp01f((pd.z - pa.z) * inv2mv + 0.5f);
            float bs[8];
            basis8(p0, p1, p2, bs);
#pragma unroll
            for (int s8 = 0; s8 < 8; ++s8)
#pragma unroll
                for (int k = 0; k < NCI; ++k)
                    acc[k][s8] += bs[s8] * fa[k];
        }
#pragma unroll
        for (int k = 0; k < NCI; ++k) {
            int ci = lane + 64 * k;
            if (ci < CIN) {
#pragma unroll
                for (int s8 = 0; s8 < 8; ++s8)
                    tsum[w][b][ci][s8] = acc[k][s8];
                tsum[w][b][ci][8] = (ci < CINF) ? feat[v * CINF + ci]
                                                : (ci == CINF ? pd.x : pd.y);
            }
        }
        if (PMODE != 0 && lane == 0) {
            int bb2 = v / bdiv;
            int ix = min(max((int)floorf(pd.x * (float)gx), 0), gx - 1);
            int iy = min(max((int)floorf(pd.y * (float)gy), 0), gy - 1);
            int it = min(max((int)floorf(pd.z * (float)gt), 0), gt - 1);
            int cl = ((bb2 * gx + ix) * gy + iy) * gt + it;
            scl[w][b] = cl;
            atomicAdd(&psum[cl * 3 + 0], pd.x);
            atomicAdd(&psum[cl * 3 + 1], pd.y);
            atomicAdd(&psum[cl * 3 + 2], pd.z);
            atomicAdd(&pcnt[cl], 1.0f);
        }
    }
    __syncthreads();

    float oA[NV][NCC], oR[NV][NCC];
#pragma unroll
    for (int b = 0; b < NV; ++b)
#pragma unroll
        for (int cc = 0; cc < NCC; ++cc) { oA[b][cc] = 0.f; oR[b][cc] = 0.f; }
    for (int s8 = 0; s8 < 8; ++s8) {
        const float* W = Wk + (size_t)s8 * CIN * COUT;
        for (int ci = 0; ci < CIN; ++ci) {
            float wv[NCC];
#pragma unroll
            for (int cc = 0; cc < NCC; ++cc)
                wv[cc] = W[(size_t)ci * COUT + cc * 64 + lane];
#pragma unroll
            for (int b = 0; b < NV; ++b) {
                float tv = tsum[w][b][ci][s8];
#pragma unroll
                for (int cc = 0; cc < NCC; ++cc) oA[b][cc] += tv * wv[cc];
            }
        }
    }
    for (int ci = 0; ci < CIN; ++ci) {
        float wv[NCC];
#pragma unroll
        for (int cc = 0; cc < NCC; ++cc)
            wv[cc] = Wr[(size_t)ci * COUT + cc * 64 + lane];
#pragma unroll
        for (int b = 0; b < NV; ++b) {
            float tv = tsum[w][b][ci][8];
#pragma unroll
            for (int cc = 0; cc < NCC; ++cc) oR[b][cc] += tv * wv[cc];
        }
    }
    for (int b = 0; b < NV; ++b) {
        int v = vbase + b;
        if (v >= V) break;
        float invn = 1.0f / fmaxf((float)cnt[v], 1.0f);
#pragma unroll
        for (int cc = 0; cc < NCC; ++cc) {
            int c = cc * 64 + lane;
            float val = fmaxf(oA[b][cc] * invn + oR[b][cc] + bias[c], 0.0f);
            if (PMODE == 0 || PMODE == 2)
                out[(size_t)v * COUT + c] = val;
            if (PMODE == 1)
                atomicMax((int*)&hp[(size_t)scl[w][b] * COUT + c], __float_as_int(val));
            if (PMODE == 2)
                atomicAdd(&hp[(size_t)scl[w][b] * COUT + c], val);
        }
    }
}

// ======================= voxel pooling: counting sort (stride-4 pos + ofs) ===========
__global__ __launch_bounds__(256) void pool_cluster_kernel(
    const float* __restrict__ p4, int ofs, const int* __restrict__ batch, int bdiv, int V,
    int nx, int ny, int nt, int* __restrict__ cl, int* __restrict__ cnt)
{
    int n = blockIdx.x * 256 + threadIdx.x;
    if (n >= V) return;
    int b = batch ? batch[n] : (n / bdiv);
    const float* pp = p4 + (size_t)n * 4 + ofs;
    float px = pp[0], py = pp[1], pt = pp[2];
    int ix = (int)floorf(px * (float)nx); ix = min(max(ix, 0), nx - 1);
    int iy = (int)floorf(py * (float)ny); iy = min(max(iy, 0), ny - 1);
    int it = (int)floorf(pt * (float)nt); it = min(max(it, 0), nt - 1);
    int c = ((b * nx + ix) * ny + iy) * nt + it;
    cl[n] = c;
    atomicAdd(&cnt[c], 1);
}

__global__ __launch_bounds__(256) void pool_scatter_kernel(
    const int* __restrict__ cl, int* __restrict__ off, int* __restrict__ order, int V, int rv)
{
    const int lo = (int)(blockIdx.x & 7) * rv;
    const int hi = lo + rv;
    const int base = (int)(blockIdx.x >> 3) << 10;
#pragma unroll
    for (int k = 0; k < 4; ++k) {
        int n = base + (k << 8) + threadIdx.x;
        if (n < V) {
            int c = __builtin_nontemporal_load(&cl[n]);
            if (c >= lo && c < hi) {
                int slot = atomicAdd(&off[c], 1);
                order[slot] = n;
            }
        }
    }
}

// ========= staged segmented max-pool: wave owns 64 sorted slots ===============
template<int COUT>
__global__ __launch_bounds__(256) void staged_pool_kernel(
    const int* __restrict__ order, const int* __restrict__ cl,
    const int* __restrict__ ioff, const int* __restrict__ icnt,
    const float* __restrict__ h, const float* __restrict__ p4, int ofs,
    float* __restrict__ hp, float* __restrict__ psum, int V)
{
    __shared__ float sh[256][COUT + 4];
    __shared__ float sp[256][3];
    __shared__ int scl2[256];
    const int t = threadIdx.x;
    const int w = t >> 6, lane = t & 63;
    const int gbase = blockIdx.x * 256 + w * 64;
    const int slot = gbase + lane;
    int myc = -1;
    if (slot < V) {
        int n = order[slot];
        myc = cl[n];
        const float* hr = h + (size_t)n * COUT;
#pragma unroll
        for (int k = 0; k < COUT / 4; ++k)
            *(float4*)&sh[w * 64 + lane][k * 4] = *(const float4*)&hr[k * 4];
        const float* pp = p4 + (size_t)n * 4 + ofs;
        sp[w * 64 + lane][0] = pp[0];
        sp[w * 64 + lane][1] = pp[1];
        sp[w * 64 + lane][2] = pp[2];
    }
    scl2[w * 64 + lane] = myc;
    __syncthreads();

    if (lane < COUT) {
        const int c = lane;
        const int sb = w * 64;
        int prev = scl2[sb];
        float run = 0.f, rp = 0.f;
        for (int i = 0; i < 64; ++i) {
            int cc = scl2[sb + i];
            if (cc != prev) {
                if (prev >= 0) {
                    int en = ioff[prev];
                    int st = en - icnt[prev];
                    if (st >= gbase && en <= gbase + 64) {
                        hp[(size_t)prev * COUT + c] = run;
                        if (c < 3) psum[prev * 3 + c] = rp;
                    } else {
                        atomicMax((int*)&hp[(size_t)prev * COUT + c], __float_as_int(run));
                        if (c < 3) atomicAdd(&psum[prev * 3 + c], rp);
                    }
                }
                prev = cc; run = 0.f; rp = 0.f;
            }
            if (cc >= 0) {
                run = fmaxf(run, sh[sb + i][c]);
                if (c < 3) rp += sp[sb + i][c];
            }
        }
        if (prev >= 0) {
            int en = ioff[prev];
            int st = en - icnt[prev];
            if (st >= gbase && en <= gbase + 64) {
                hp[(size_t)prev * COUT + c] = run;
                if (c < 3) psum[prev * 3 + c] = rp;
            } else {
                atomicMax((int*)&hp[(size_t)prev * COUT + c], __float_as_int(run));
                if (c < 3) atomicAdd(&psum[prev * 3 + c], rp);
            }
        }
    }
}

// ======================= pool finalize (float4 pos outputs) =======================
__global__ __launch_bounds__(256) void finalize_posI_kernel(
    const float* __restrict__ psum, const int* __restrict__ icnt,
    float4* __restrict__ pos_out, int Vc)
{
    int c = blockIdx.x * 256 + threadIdx.x;
    if (c >= Vc) return;
    float m = fmaxf((float)icnt[c], 1.0f);
    pos_out[c] = make_float4(psum[c * 3 + 0] / m, psum[c * 3 + 1] / m,
                             psum[c * 3 + 2] / m, 0.f);
}

__global__ __launch_bounds__(256) void finalize_pos_kernel(
    const float* __restrict__ psum, const float* __restrict__ pcnt,
    float4* __restrict__ pos_out, int Vc)
{
    int c = blockIdx.x * 256 + threadIdx.x;
    if (c >= Vc) return;
    float m = fmaxf(pcnt[c], 1.0f);
    pos_out[c] = make_float4(psum[c * 3 + 0] / m, psum[c * 3 + 1] / m,
                             psum[c * 3 + 2] / m, 0.f);
}

__global__ __launch_bounds__(256) void finalize_mean_kernel(
    const float* __restrict__ hsum, const float* __restrict__ psum,
    const float* __restrict__ pcnt,
    float* __restrict__ hout, float4* __restrict__ pos_out, int Vc)
{
    int g = blockIdx.x * 256 + threadIdx.x;
    if (g >= Vc * 128) return;
    int c = g >> 7, ch = g & 127;
    float m = fmaxf(pcnt[c], 1.0f);
    hout[g] = hsum[g] / m;
    if (ch == 0)
        pos_out[c] = make_float4(psum[c * 3 + 0] / m, psum[c * 3 + 1] / m,
                                 psum[c * 3 + 2] / m, 0.f);
}

// ======================= host =======================
extern "C" void kernel_launch(void* const* d_in, const int* in_sizes, int n_in,
                              void* d_out, int out_size, void* d_ws, size_t ws_size,
                              hipStream_t stream)
{
    (void)in_sizes; (void)n_in; (void)out_size;
    const float* x    = (const float*)d_in[0];
    const float* pos0 = (const float*)d_in[1];
    const int*   bat  = (const int*)d_in[2];
    const int* e1 = (const int*)d_in[3];
    const int* e2 = (const int*)d_in[4];
    const int* e3 = (const int*)d_in[5];
    const int* e4 = (const int*)d_in[6];
    const int* e5 = (const int*)d_in[7];
    const float* W1 = (const float*)d_in[8],  *R1 = (const float*)d_in[9],  *B1 = (const float*)d_in[10];
    const float* W2 = (const float*)d_in[11], *R2 = (const float*)d_in[12], *B2 = (const float*)d_in[13];
    const float* W3 = (const float*)d_in[14], *R3 = (const float*)d_in[15], *B3 = (const float*)d_in[16];
    const float* W4 = (const float*)d_in[17], *R4 = (const float*)d_in[18], *B4 = (const float*)d_in[19];
    const float* W5 = (const float*)d_in[20], *R5 = (const float*)d_in[21], *B5 = (const float*)d_in[22];

    const int E1 = 3600000, E2 = 786432, E3 = 196608, E4 = 24576, E5 = 3072;

    if (ws_size < (size_t)21800000 * sizeof(float)) return;
    float* ws = (float*)d_ws;
    // pools (floats): P0 12.6M | P1 6.3M | P2 1.6M | P3 1.0M ints | P4 0.3M
    float* P0 = ws;
    float* P1 = ws + 12600000;
    float* P2 = ws + 18900000;
    int*   P3 = (int*)(ws + 20500000);
    float* P4 = ws + 21500000;
    int* GCNT   = P3 + 990000;
    int* GCUR   = P3 + 990256;
    int* SCR_BS = P3 + 999744;
    int* SCR_BO = SCR_BS + 96;

    float* out3 = (float*)d_out;           // 1536*128
    float* hfin = (float*)d_out + 196608;  // 192*128

#define MSI(p, ni) hipMemsetAsync((p), 0, (size_t)(ni) * sizeof(int), stream)

#define SCAN(cntp, offp, Vn)                                                                     \
    {                                                                                            \
        int nb_ = ((Vn) + 4095) / 4096;                                                          \
        if (nb_ <= 1) {                                                                          \
            scan1_kernel<<<1, 256, 0, stream>>>((cntp), (offp), nullptr, (Vn));                  \
        } else {                                                                                 \
            scan1_kernel<<<nb_, 256, 0, stream>>>((cntp), (offp), SCR_BS, (Vn));                 \
            scan1_kernel<<<1, 256, 0, stream>>>(SCR_BS, SCR_BO, nullptr, nb_);                   \
            scan_add_kernel<<<((Vn) + 255) / 256, 256, 0, stream>>>((offp), SCR_BO, (Vn));       \
        }                                                                                        \
    }

#define BSORT(cntP, offP, srcP, stP, ep, En, Vn, SHIFT, NB)                                      \
    {                                                                                            \
        MSI(GCNT, 256);                                                                          \
        bin_count_kernel<<<((En) + 4095) / 4096, 256, 0, stream>>>((ep) + (En), GCNT, En, SHIFT);\
        scan1_kernel<<<1, 256, 0, stream>>>(GCNT, GCUR, nullptr, NB);                            \
        bin_scatter_kernel<<<((En) + 4095) / 4096, 256, 0, stream>>>(                            \
            (ep), (ep) + (En), GCUR, stP, En, SHIFT);                                            \
        bucket_csr_kernel<<<NB, 1024, 0, stream>>>(                                              \
            GCUR, GCNT, stP, cntP, offP, srcP, Vn, SHIFT);                                       \
    }

#define ESORT(base, ep, En, Vn)                                                                  \
    int* cnt_ = (base);                                                                          \
    int* off_ = cnt_ + (Vn);                                                                     \
    int* src_ = off_ + (Vn);                                                                     \
    MSI(cnt_, (Vn));                                                                             \
    edge_count_kernel<<<((En) + 255) / 256, 256, 0, stream>>>((ep) + (En), cnt_, En);            \
    SCAN(cnt_, off_, (Vn));                                                                      \
    edge_scatter_kernel<<<8 * (((En) + 1023) / 1024), 256, 0, stream>>>(                         \
        (ep), (ep) + (En), off_, src_, En, (Vn) >> 3)

    // staged pool: counting sort by cluster, then staged segmented reduce.
#define SPOOL(ICLp, IORDp, ICNTp, IOFFp, p4src, ofsv, batp, bdiv, Vn, Vc, NX, NY, NT, COUTV, \
              hsrc, hpool, psumP, posdst)                                                   \
    {                                                                                       \
        MSI(ICNTp, (Vc));                                                                   \
        pool_cluster_kernel<<<((Vn) + 255) / 256, 256, 0, stream>>>(                        \
            p4src, ofsv, batp, bdiv, Vn, NX, NY, NT, ICLp, ICNTp);                          \
        SCAN(ICNTp, IOFFp, (Vc));                                                           \
        pool_scatter_kernel<<<8 * (((Vn) + 1023) / 1024), 256, 0, stream>>>(                \
            ICLp, IOFFp, IORDp, Vn, (Vc) >> 3);                                             \
        MSI(hpool, (size_t)(Vc) * (COUTV));                                                 \
        MSI(psumP, (size_t)(Vc) * 3);                                                       \
        staged_pool_kernel<COUTV><<<((Vn) + 255) / 256, 256, 0, stream>>>(                  \
            IORDp, ICLp, IOFFp, ICNTp, hsrc, p4src, ofsv, hpool, psumP, Vn);                \
        finalize_posI_kernel<<<((Vc) + 255) / 256, 256, 0, stream>>>(                       \
            psumP, ICNTp, (float4*)(posdst), Vc);                                           \
    }

    // ---------- Layer 1: 300000 nodes, CIN=3, COUT=16 -> dense h1; staged pool (64,48,8) --
    {
        int* cnt1 = (int*)P0;
        int* off1 = cnt1 + 300000;
        int* src1 = off1 + 300000;
        int2* st1 = (int2*)(src1 + 3600000);      // 3.6M int2 = 7.2M ints
        float4* xp4 = (float4*)(P0 + 11400000);
        BSORT(cnt1, off1, src1, st1, e1, E1, 300000, 11, 147);
        pack_xpos_kernel<<<(300000 + 255) / 256, 256, 0, stream>>>(x, pos0, xp4, 300000);
        l1_fused_kernel<<<(300000 + 255) / 256, 256, 0, stream>>>(
            off1, cnt1, src1, xp4, W1, R1, B1, P1, 20.0f, 300000);
        // CSR/staging dead (xp4 alive). Pool: ints in P3; hp1->P2; psum1->P0; pos2_4->P0+300000.
        int* ICL1  = P3;
        int* IORD1 = P3 + 300000;
        int* ICNT1 = P3 + 600000;
        int* IOFF1 = P3 + 698304;
        SPOOL(ICL1, IORD1, ICNT1, IOFF1, (const float*)xp4, 1, bat, 0, 300000, 98304,
              64, 48, 8, 16, P1, P2, P0, P0 + 300000);
    }
    float4* pos2_4 = (float4*)(P0 + 300000);     // 98304*4 floats
    // ---------- Layer 2: 98304 nodes, CINF=16, COUT=64 -> dense h2; staged pool (32,24,4) -
    {
        int* cnt2 = P3;
        int* off2 = cnt2 + 98304;
        int* src2 = off2 + 98304;
        int2* st2 = (int2*)(P0 + 1000000);       // staging clear of pos2_4
        BSORT(cnt2, off2, src2, st2, e2, E2, 98304, 10, 96);
        tsum16_layer_kernel<4><<<98304 / 16, 256, 0, stream>>>(
            off2, cnt2, src2, pos2_4, P2, W2, R2, B2, P1, 10.0f, 98304);
        // CSR2 dead -> reuse P3 for pool sort. hp2->P2; psum2->P2+786432; pos3_4->P4.
        int* ICL2  = P3;
        int* IORD2 = P3 + 98304;
        int* ICNT2 = P3 + 196608;
        int* IOFF2 = P3 + 208896;
        SPOOL(ICL2, IORD2, ICNT2, IOFF2, (const float*)pos2_4, 0, nullptr, 24576,
              98304, 12288, 32, 24, 4, 64, P1, P2, P2 + 786432, P4);
    }
    // ---------- Layer 3: 12288 nodes, CINF=64, COUT=128; fused atomic max-pool (16,12,2) --
    {
        ESORT(P3, e3, E3, 12288);
        float* HP3 = P1;                    // 1536*128 = 196608
        float* PS3 = P1 + 196608;           // 1536*3
        float* PC3 = P1 + 201216;           // 1536
        MSI(P1, 202752);
        tsum_layer_kernel<64, 128, 4, 4, 1><<<12288 / 16, 256, 0, stream>>>(
            off_, cnt_, src_, (const float4*)P4, P2, W3, R3, B3, nullptr,
            HP3, PS3, PC3, 6.0f, 12288, 16, 12, 2, 3072);
        finalize_pos_kernel<<<(1536 + 255) / 256, 256, 0, stream>>>(
            PS3, PC3, (float4*)P0, 1536);
    }
    // ---------- Layer 4: 1536 nodes, CINF=128, COUT=128 -> out3; fused mean-pool (8,6,1) --
    {
        ESORT(P3, e4, E4, 1536);
        float* HS4 = P2;                    // 192*128 = 24576 (sums)
        float* PS4 = P2 + 24576;            // 192*3
        float* PC4 = P2 + 25152;            // 192
        MSI(P2, 25344);
        tsum_layer_kernel<128, 128, 2, 4, 2><<<1536 / 8, 256, 0, stream>>>(
            off_, cnt_, src_, (const float4*)P0, P1, W4, R4, B4, out3,
            HS4, PS4, PC4, 3.0f, 1536, 8, 6, 1, 384);
        finalize_mean_kernel<<<(192 * 128 + 255) / 256, 256, 0, stream>>>(
            HS4, PS4, PC4, P1, (float4*)(P0 + 100000), 192);
    }
    // ---------- Layer 5: 192 nodes, CINF=128, COUT=128 -> hfin (no pool) ----------
    {
        ESORT(P3, e5, E5, 192);
        tsum_layer_kernel<128, 128, 2, 4, 0><<<192 / 8, 256, 0, stream>>>(
            off_, cnt_, src_, (const float4*)(P0 + 100000), P1, W5, R5, B5, hfin,
            nullptr, nullptr, nullptr, 1.5f, 192, 1, 1, 1, 1);
    }
#undef SPOOL
#undef ESORT
#undef BSORT
#undef SCAN
#undef MSI
}

// Round 15
// 840.882 us; speedup vs baseline: 1.0351x; 1.0351x over previous
//
#include <hip/hip_runtime.h>
#include <cstdint>

__device__ __forceinline__ float clamp01f(float v) { return fminf(fmaxf(v, 0.0f), 1.0f); }

// factored trilinear basis: 12 mults for the 8 corner weights
__device__ __forceinline__ void basis8(float p0, float p1, float p2, float* bs)
{
    float q0 = 1.f - p0, q1 = 1.f - p1, q2 = 1.f - p2;
    float t00 = q0 * q1, t10 = p0 * q1, t01 = q0 * p1, t11 = p0 * p1;
    bs[0] = t00 * q2; bs[1] = t10 * q2; bs[2] = t01 * q2; bs[3] = t11 * q2;
    bs[4] = t00 * p2; bs[5] = t10 * p2; bs[6] = t01 * p2; bs[7] = t11 * p2;
}

// ======================= legacy CSR build (layers 3-5, small E) =======================
__global__ __launch_bounds__(256) void edge_count_kernel(
    const int* __restrict__ edst, int* __restrict__ cnt, int E)
{
    int e = blockIdx.x * 256 + threadIdx.x;
    if (e < E) atomicAdd(&cnt[__builtin_nontemporal_load(&edst[e])], 1);
}

__global__ __launch_bounds__(256) void edge_scatter_kernel(
    const int* __restrict__ esrc, const int* __restrict__ edst,
    int* __restrict__ off, int* __restrict__ srcs, int E, int rv)
{
    const int lo = (int)(blockIdx.x & 7) * rv;
    const int hi = lo + rv;
    const int base = (int)(blockIdx.x >> 3) << 10;
#pragma unroll
    for (int k = 0; k < 4; ++k) {
        int e = base + (k << 8) + threadIdx.x;
        if (e < E) {
            int d = __builtin_nontemporal_load(&edst[e]);
            if (d >= lo && d < hi) {
                int s = __builtin_nontemporal_load(&esrc[e]);
                int slot = atomicAdd(&off[d], 1);
                srcs[slot] = s;
            }
        }
    }
}

// ============== hierarchical exclusive scan ==============
__global__ __launch_bounds__(256) void scan1_kernel(
    const int* __restrict__ cnt, int* __restrict__ off, int* __restrict__ bsum, int V)
{
    __shared__ int lds[4096];
    __shared__ int ssum[256];
    const int t = threadIdx.x;
    const int base = blockIdx.x * 4096;
    for (int i = t; i < 4096; i += 256) {
        int g = base + i;
        lds[i] = (g < V) ? cnt[g] : 0;
    }
    __syncthreads();
    int loc[16];
    int s = 0;
#pragma unroll
    for (int k = 0; k < 16; ++k) { loc[k] = s; s += lds[t * 16 + k]; }
    ssum[t] = s;
    __syncthreads();
    for (int d = 1; d < 256; d <<= 1) {
        int v = (t >= d) ? ssum[t - d] : 0;
        __syncthreads();
        ssum[t] += v;
        __syncthreads();
    }
    const int tbase = (t == 0) ? 0 : ssum[t - 1];
    if (t == 255 && bsum) bsum[blockIdx.x] = ssum[255];
#pragma unroll
    for (int k = 0; k < 16; ++k) lds[t * 16 + k] = tbase + loc[k];
    __syncthreads();
    for (int i = t; i < 4096; i += 256) {
        int g = base + i;
        if (g < V) off[g] = lds[i];
    }
}

__global__ __launch_bounds__(256) void scan_add_kernel(
    int* __restrict__ off, const int* __restrict__ bso, int V)
{
    int g = blockIdx.x * 256 + threadIdx.x;
    if (g < V) off[g] += bso[g >> 12];
}

// ======================= bucketed CSR build (L1, L2) =======================
__global__ __launch_bounds__(256) void bin_count_kernel(
    const int* __restrict__ edst, int* __restrict__ gcnt, int E, int shift)
{
    __shared__ int h[256];
    const int t = threadIdx.x;
    h[t] = 0;
    __syncthreads();
    const int base = blockIdx.x << 12;
#pragma unroll
    for (int k = 0; k < 16; ++k) {
        int e = base + (k << 8) + t;
        if (e < E) {
            int d = __builtin_nontemporal_load(&edst[e]);
            atomicAdd(&h[d >> shift], 1);
        }
    }
    __syncthreads();
    if (h[t]) atomicAdd(&gcnt[t], h[t]);
}

// staging packed as int2 (dst, src): one 8B store per edge, paired locality on read.
__global__ __launch_bounds__(256) void bin_scatter_kernel(
    const int* __restrict__ esrc, const int* __restrict__ edst,
    int* __restrict__ gcur, int2* __restrict__ st, int E, int shift)
{
    __shared__ int d_l[4096];
    __shared__ int s_l[4096];
    __shared__ int h[256];
    __shared__ int rbase[256];
    const int t = threadIdx.x;
    h[t] = 0;
    __syncthreads();
    const int base = blockIdx.x << 12;
#pragma unroll
    for (int k = 0; k < 16; ++k) {
        int i = (k << 8) + t;
        int e = base + i;
        if (e < E) {
            int d = __builtin_nontemporal_load(&edst[e]);
            int s = __builtin_nontemporal_load(&esrc[e]);
            d_l[i] = d; s_l[i] = s;
            atomicAdd(&h[d >> shift], 1);
        }
    }
    __syncthreads();
    rbase[t] = h[t] ? atomicAdd(&gcur[t], h[t]) : 0;
    h[t] = 0;   // reuse as cursor
    __syncthreads();
#pragma unroll
    for (int k = 0; k < 16; ++k) {
        int i = (k << 8) + t;
        int e = base + i;
        if (e < E) {
            int d = d_l[i];
            int b = d >> shift;
            int r = atomicAdd(&h[b], 1);
            st[rbase[b] + r] = make_int2(d, s_l[i]);
        }
    }
}

__global__ __launch_bounds__(1024) void bucket_csr_kernel(
    const int* __restrict__ gcur, const int* __restrict__ gcnt,
    const int2* __restrict__ st,
    int* __restrict__ cnt, int* __restrict__ off, int* __restrict__ srcs,
    int V, int shift)
{
    __shared__ int h[2048];
    __shared__ int o[2048];
    __shared__ int ps[1024];
    const int t = threadIdx.x;
    const int b = blockIdx.x;
    const int v0 = b << shift;
    const int nv = min(1 << shift, V - v0);
    const int s1 = gcur[b];
    const int s0 = s1 - gcnt[b];
    h[t] = 0; h[t + 1024] = 0;
    __syncthreads();
    for (int i = s0 + t; i < s1; i += 1024)
        atomicAdd(&h[st[i].x - v0], 1);
    __syncthreads();
    int a = h[2 * t], b2 = h[2 * t + 1];
    ps[t] = a + b2;
    __syncthreads();
    for (int d = 1; d < 1024; d <<= 1) {
        int v = (t >= d) ? ps[t - d] : 0;
        __syncthreads();
        ps[t] += v;
        __syncthreads();
    }
    int pb = (t == 0) ? 0 : ps[t - 1];
    o[2 * t] = pb;
    o[2 * t + 1] = pb + a;
    __syncthreads();
    for (int i = t; i < nv; i += 1024) {
        int hv = h[i];
        cnt[v0 + i] = hv;
        off[v0 + i] = s0 + o[i] + hv;   // segment END convention
    }
    __syncthreads();
    for (int i = s0 + t; i < s1; i += 1024) {
        int2 e = st[i];
        int r = atomicAdd(&o[e.x - v0], 1);
        srcs[s0 + r] = e.y;
    }
}

// ======================= pack (x, pos) into float4 for layer-1 gathers =======
__global__ __launch_bounds__(256) void pack_xpos_kernel(
    const float* __restrict__ x, const float* __restrict__ pos,
    float4* __restrict__ xp, int V)
{
    int n = blockIdx.x * 256 + threadIdx.x;
    if (n >= V) return;
    xp[n] = make_float4(x[n], pos[n * 3 + 0], pos[n * 3 + 1], pos[n * 3 + 2]);
}

// ========== Layer-1 fused, tsum, DENSE output; 4-edge unrolled gather ==========
__device__ __forceinline__ void l1_edge_acc(
    const float4 d, const float4 a, float inv2mv, float ts[8][3])
{
    float p0 = clamp01f((d.y - a.y) * inv2mv + 0.5f);
    float p1 = clamp01f((d.z - a.z) * inv2mv + 0.5f);
    float p2 = clamp01f((d.w - a.w) * inv2mv + 0.5f);
    float bs[8];
    basis8(p0, p1, p2, bs);
#pragma unroll
    for (int s8 = 0; s8 < 8; ++s8) {
        ts[s8][0] += bs[s8] * a.x;
        ts[s8][1] += bs[s8] * a.y;
        ts[s8][2] += bs[s8] * a.z;
    }
}

__global__ __launch_bounds__(256) void l1_fused_kernel(
    const int* __restrict__ off, const int* __restrict__ cnt, const int* __restrict__ srcs,
    const float4* __restrict__ xp,
    const float* __restrict__ Wk, const float* __restrict__ Wr,
    const float* __restrict__ bias, float* __restrict__ out,
    float inv2mv, int V)
{
    __shared__ float sWk[384];
    __shared__ float sWr[48];
    __shared__ float sB[16];
    const int t = threadIdx.x;
    for (int i = t; i < 384; i += 256) sWk[i] = Wk[i];
    if (t < 48) sWr[t] = Wr[t];
    if (t < 16) sB[t] = bias[t];
    __syncthreads();
    const int v = blockIdx.x * 256 + t;
    if (v >= V) return;
    const float4 d = xp[v];  // x, px, py, pt
    const int e1 = off[v];
    const int n = cnt[v];
    float ts[8][3];
#pragma unroll
    for (int s8 = 0; s8 < 8; ++s8) { ts[s8][0] = 0.f; ts[s8][1] = 0.f; ts[s8][2] = 0.f; }
    int j = e1 - n;
    for (; j + 3 < e1; j += 4) {
        float4 a0 = xp[srcs[j]];
        float4 a1 = xp[srcs[j + 1]];
        float4 a2 = xp[srcs[j + 2]];
        float4 a3 = xp[srcs[j + 3]];
        l1_edge_acc(d, a0, inv2mv, ts);
        l1_edge_acc(d, a1, inv2mv, ts);
        l1_edge_acc(d, a2, inv2mv, ts);
        l1_edge_acc(d, a3, inv2mv, ts);
    }
    for (; j < e1; ++j)
        l1_edge_acc(d, xp[srcs[j]], inv2mv, ts);
    const float invn = 1.0f / fmaxf((float)n, 1.0f);
    float rr[16];
#pragma unroll
    for (int c = 0; c < 16; ++c) {
        float m = 0.f;
#pragma unroll
        for (int s8 = 0; s8 < 8; ++s8)
            m += ts[s8][0] * sWk[s8 * 48 + c]
               + ts[s8][1] * sWk[s8 * 48 + 16 + c]
               + ts[s8][2] * sWk[s8 * 48 + 32 + c];
        float r = m * invn + d.x * sWr[c] + d.y * sWr[16 + c] + d.z * sWr[32 + c] + sB[c];
        rr[c] = fmaxf(r, 0.0f);
    }
    float4* op = (float4*)(out + (size_t)v * 16);
#pragma unroll
    for (int k = 0; k < 4; ++k)
        op[k] = make_float4(rr[4 * k], rr[4 * k + 1], rr[4 * k + 2], rr[4 * k + 3]);
}

// ========== Layer-2 tsum, quarter-wave-per-node, 4-edge unroll (round-13 form) =======
__device__ __forceinline__ void l2_edge_acc(
    const float4 pd, const float4 pa, float fa, int l16, float inv2mv,
    float* accF, float* accP)
{
    float p0 = clamp01f((pd.x - pa.x) * inv2mv + 0.5f);
    float p1 = clamp01f((pd.y - pa.y) * inv2mv + 0.5f);
    float p2 = clamp01f((pd.z - pa.z) * inv2mv + 0.5f);
    float bs[8];
    basis8(p0, p1, p2, bs);
    const float fp = (l16 == 0) ? pa.x : ((l16 == 1) ? pa.y : 0.f);
#pragma unroll
    for (int s8 = 0; s8 < 8; ++s8) {
        accF[s8] += bs[s8] * fa;
        accP[s8] += bs[s8] * fp;
    }
}

template<int NW>
__global__ __launch_bounds__(64 * NW) void tsum16_layer_kernel(
    const int* __restrict__ off, const int* __restrict__ cnt, const int* __restrict__ srcs,
    const float4* __restrict__ pos4, const float* __restrict__ feat,
    const float* __restrict__ Wk, const float* __restrict__ Wr,
    const float* __restrict__ bias, float* __restrict__ out,
    float inv2mv, int V)
{
    __shared__ float tsum[NW][4][18][9];
    const int tid = threadIdx.x;
    const int w = tid >> 6, lane = tid & 63;
    const int q = lane >> 4, l16 = lane & 15;
    const int vbase = (blockIdx.x * NW + w) * 4;
    const int v = vbase + q;        // V divisible by 4*NW -> always < V

    const float4 pd = pos4[v];
    const int e1 = off[v];
    const int n = cnt[v];
    float accF[8], accP[8];
#pragma unroll
    for (int s8 = 0; s8 < 8; ++s8) { accF[s8] = 0.f; accP[s8] = 0.f; }
    int j = e1 - n;
    for (; j + 3 < e1; j += 4) {
        const int s0 = srcs[j], s1 = srcs[j + 1], s2 = srcs[j + 2], s3 = srcs[j + 3];
        const float4 pa = pos4[s0];
        const float4 pb = pos4[s1];
        const float4 pc = pos4[s2];
        const float4 pe = pos4[s3];
        const float fa = feat[s0 * 16 + l16];
        const float fb = feat[s1 * 16 + l16];
        const float fc = feat[s2 * 16 + l16];
        const float fe = feat[s3 * 16 + l16];
        l2_edge_acc(pd, pa, fa, l16, inv2mv, accF, accP);
        l2_edge_acc(pd, pb, fb, l16, inv2mv, accF, accP);
        l2_edge_acc(pd, pc, fc, l16, inv2mv, accF, accP);
        l2_edge_acc(pd, pe, fe, l16, inv2mv, accF, accP);
    }
    for (; j < e1; ++j) {
        const int s = srcs[j];
        const float4 pa = pos4[s];
        const float fa = feat[s * 16 + l16];
        l2_edge_acc(pd, pa, fa, l16, inv2mv, accF, accP);
    }
#pragma unroll
    for (int s8 = 0; s8 < 8; ++s8)
        tsum[w][q][l16][s8] = accF[s8];
    tsum[w][q][l16][8] = feat[v * 16 + l16];
    if (l16 < 2) {
#pragma unroll
        for (int s8 = 0; s8 < 8; ++s8)
            tsum[w][q][16 + l16][s8] = accP[s8];
        tsum[w][q][16 + l16][8] = (l16 == 0) ? pd.x : pd.y;
    }
    __syncthreads();

    float oA[4], oR[4];
#pragma unroll
    for (int b = 0; b < 4; ++b) { oA[b] = 0.f; oR[b] = 0.f; }
    for (int s8 = 0; s8 < 8; ++s8) {
        const float* W = Wk + (size_t)s8 * 18 * 64;
        for (int ci = 0; ci < 18; ++ci) {
            float wv = W[ci * 64 + lane];
#pragma unroll
            for (int b = 0; b < 4; ++b)
                oA[b] += tsum[w][b][ci][s8] * wv;
        }
    }
    for (int ci = 0; ci < 18; ++ci) {
        float wv = Wr[ci * 64 + lane];
#pragma unroll
        for (int b = 0; b < 4; ++b)
            oR[b] += tsum[w][b][ci][8] * wv;
    }
    const float bi = bias[lane];
#pragma unroll
    for (int b = 0; b < 4; ++b) {
        int vv = vbase + b;
        float invn = 1.0f / fmaxf((float)cnt[vv], 1.0f);
        out[(size_t)vv * 64 + lane] = fmaxf(oA[b] * invn + oR[b] + bi, 0.0f);
    }
}

// ========== Generic tsum layer (L3-5), 2-edge unroll, factored basis, fused pooling ==
// PMODE: 0 = dense out only (L5), 1 = atomic max-pool only (L3),
//        2 = dense out + atomic mean-pool sums (L4).
template<int CINF, int COUT, int NV, int NW, int PMODE>
__global__ __launch_bounds__(64 * NW) void tsum_layer_kernel(
    const int* __restrict__ off, const int* __restrict__ cnt, const int* __restrict__ srcs,
    const float4* __restrict__ pos4, const float* __restrict__ feat,
    const float* __restrict__ Wk, const float* __restrict__ Wr,
    const float* __restrict__ bias, float* __restrict__ out,
    float* __restrict__ hp, float* __restrict__ psum, float* __restrict__ pcnt,
    float inv2mv, int V, int gx, int gy, int gt, int bdiv)
{
    constexpr int CIN = CINF + 2;
    constexpr int NCI = (CIN + 63) / 64;
    constexpr int NCC = COUT / 64;
    __shared__ float tsum[NW][NV][CIN][9];
    __shared__ int scl[NW][NV];
    const int tid = threadIdx.x;
    const int w = tid >> 6, lane = tid & 63;
    const int vbase = (blockIdx.x * NW + w) * NV;

    for (int b = 0; b < NV; ++b) {
        const int v = vbase + b;
        if (v >= V) break;
        const float4 pd = pos4[v];
        float acc[NCI][8];
#pragma unroll
        for (int k = 0; k < NCI; ++k)
#pragma unroll
            for (int s8 = 0; s8 < 8; ++s8) acc[k][s8] = 0.f;
        const int e1 = off[v];
        int j = e1 - cnt[v];
        for (; j + 1 < e1; j += 2) {
            const int s0 = srcs[j], s1 = srcs[j + 1];
            const float4 pa = pos4[s0];
            const float4 pb = pos4[s1];
            float fa[NCI], fb[NCI];
#pragma unroll
            for (int k = 0; k < NCI; ++k) {
                int ci = lane + 64 * k;
                fa[k] = (ci < CINF) ? feat[s0 * CINF + ci]
                       : (ci == CINF ? pa.x : (ci == CINF + 1 ? pa.y : 0.f));
                fb[k] = (ci < CINF) ? feat[s1 * CINF + ci]
                       : (ci == CINF ? pb.x : (ci == CINF + 1 ? pb.y : 0.f));
            }
            float pa0 = clamp01f((pd.x - pa.x) * inv2mv + 0.5f);
            float pa1 = clamp01f((pd.y - pa.y) * inv2mv + 0.5f);
            float pa2 = clamp01f((pd.z - pa.z) * inv2mv + 0.5f);
            float pb0 = clamp01f((pd.x - pb.x) * inv2mv + 0.5f);
            float pb1 = clamp01f((pd.y - pb.y) * inv2mv + 0.5f);
            float pb2 = clamp01f((pd.z - pb.z) * inv2mv + 0.5f);
            float ba[8], bb[8];
            basis8(pa0, pa1, pa2, ba);
            basis8(pb0, pb1, pb2, bb);
#pragma unroll
            for (int s8 = 0; s8 < 8; ++s8)
#pragma unroll
                for (int k = 0; k < NCI; ++k)
                    acc[k][s8] += ba[s8] * fa[k] + bb[s8] * fb[k];
        }
        if (j < e1) {
            const int s = srcs[j];
            const float4 pa = pos4[s];
            float fa[NCI];
#pragma unroll
            for (int k = 0; k < NCI; ++k) {
                int ci = lane + 64 * k;
                fa[k] = (ci < CINF) ? feat[s * CINF + ci]
                       : (ci == CINF ? pa.x : (ci == CINF + 1 ? pa.y : 0.f));
            }
            float p0 = clamp01f((pd.x - pa.x) * inv2mv + 0.5f);
            float p1 = clamp01f((pd.y - pa.y) * inv2mv + 0.5f);
            float p2 = clamp01f((pd.z - pa.z) * inv2mv + 0.5f);
            float bs[8];
            basis8(p0, p1, p2, bs);
#pragma unroll
            for (int s8 = 0; s8 < 8; ++s8)
#pragma unroll
                for (int k = 0; k < NCI; ++k)
                    acc[k][s8] += bs[s8] * fa[k];
        }
#pragma unroll
        for (int k = 0; k < NCI; ++k) {
            int ci = lane + 64 * k;
            if (ci < CIN) {
#pragma unroll
                for (int s8 = 0; s8 < 8; ++s8)
                    tsum[w][b][ci][s8] = acc[k][s8];
                tsum[w][b][ci][8] = (ci < CINF) ? feat[v * CINF + ci]
                                                : (ci == CINF ? pd.x : pd.y);
            }
        }
        if (PMODE != 0 && lane == 0) {
            int bb2 = v / bdiv;
            int ix = min(max((int)floorf(pd.x * (float)gx), 0), gx - 1);
            int iy = min(max((int)floorf(pd.y * (float)gy), 0), gy - 1);
            int it = min(max((int)floorf(pd.z * (float)gt), 0), gt - 1);
            int cl = ((bb2 * gx + ix) * gy + iy) * gt + it;
            scl[w][b] = cl;
            atomicAdd(&psum[cl * 3 + 0], pd.x);
            atomicAdd(&psum[cl * 3 + 1], pd.y);
            atomicAdd(&psum[cl * 3 + 2], pd.z);
            atomicAdd(&pcnt[cl], 1.0f);
        }
    }
    __syncthreads();

    float oA[NV][NCC], oR[NV][NCC];
#pragma unroll
    for (int b = 0; b < NV; ++b)
#pragma unroll
        for (int cc = 0; cc < NCC; ++cc) { oA[b][cc] = 0.f; oR[b][cc] = 0.f; }
    for (int s8 = 0; s8 < 8; ++s8) {
        const float* W = Wk + (size_t)s8 * CIN * COUT;
        for (int ci = 0; ci < CIN; ++ci) {
            float wv[NCC];
#pragma unroll
            for (int cc = 0; cc < NCC; ++cc)
                wv[cc] = W[(size_t)ci * COUT + cc * 64 + lane];
#pragma unroll
            for (int b = 0; b < NV; ++b) {
                float tv = tsum[w][b][ci][s8];
#pragma unroll
                for (int cc = 0; cc < NCC; ++cc) oA[b][cc] += tv * wv[cc];
            }
        }
    }
    for (int ci = 0; ci < CIN; ++ci) {
        float wv[NCC];
#pragma unroll
        for (int cc = 0; cc < NCC; ++cc)
            wv[cc] = Wr[(size_t)ci * COUT + cc * 64 + lane];
#pragma unroll
        for (int b = 0; b < NV; ++b) {
            float tv = tsum[w][b][ci][8];
#pragma unroll
            for (int cc = 0; cc < NCC; ++cc) oR[b][cc] += tv * wv[cc];
        }
    }
    for (int b = 0; b < NV; ++b) {
        int v = vbase + b;
        if (v >= V) break;
        float invn = 1.0f / fmaxf((float)cnt[v], 1.0f);
#pragma unroll
        for (int cc = 0; cc < NCC; ++cc) {
            int c = cc * 64 + lane;
            float val = fmaxf(oA[b][cc] * invn + oR[b][cc] + bias[c], 0.0f);
            if (PMODE == 0 || PMODE == 2)
                out[(size_t)v * COUT + c] = val;
            if (PMODE == 1)
                atomicMax((int*)&hp[(size_t)scl[w][b] * COUT + c], __float_as_int(val));
            if (PMODE == 2)
                atomicAdd(&hp[(size_t)scl[w][b] * COUT + c], val);
        }
    }
}

// ======================= voxel pooling: counting sort (stride-4 pos + ofs) ===========
__global__ __launch_bounds__(256) void pool_cluster_kernel(
    const float* __restrict__ p4, int ofs, const int* __restrict__ batch, int bdiv, int V,
    int nx, int ny, int nt, int* __restrict__ cl, int* __restrict__ cnt)
{
    int n = blockIdx.x * 256 + threadIdx.x;
    if (n >= V) return;
    int b = batch ? batch[n] : (n / bdiv);
    const float* pp = p4 + (size_t)n * 4 + ofs;
    float px = pp[0], py = pp[1], pt = pp[2];
    int ix = (int)floorf(px * (float)nx); ix = min(max(ix, 0), nx - 1);
    int iy = (int)floorf(py * (float)ny); iy = min(max(iy, 0), ny - 1);
    int it = (int)floorf(pt * (float)nt); it = min(max(it, 0), nt - 1);
    int c = ((b * nx + ix) * ny + iy) * nt + it;
    cl[n] = c;
    atomicAdd(&cnt[c], 1);
}

__global__ __launch_bounds__(256) void pool_scatter_kernel(
    const int* __restrict__ cl, int* __restrict__ off, int* __restrict__ order, int V, int rv)
{
    const int lo = (int)(blockIdx.x & 7) * rv;
    const int hi = lo + rv;
    const int base = (int)(blockIdx.x >> 3) << 10;
#pragma unroll
    for (int k = 0; k < 4; ++k) {
        int n = base + (k << 8) + threadIdx.x;
        if (n < V) {
            int c = __builtin_nontemporal_load(&cl[n]);
            if (c >= lo && c < hi) {
                int slot = atomicAdd(&off[c], 1);
                order[slot] = n;
            }
        }
    }
}

// ========= staged segmented max-pool: wave owns 64 sorted slots ===============
template<int COUT>
__global__ __launch_bounds__(256) void staged_pool_kernel(
    const int* __restrict__ order, const int* __restrict__ cl,
    const int* __restrict__ ioff, const int* __restrict__ icnt,
    const float* __restrict__ h, const float* __restrict__ p4, int ofs,
    float* __restrict__ hp, float* __restrict__ psum, int V)
{
    __shared__ float sh[256][COUT + 4];
    __shared__ float sp[256][3];
    __shared__ int scl2[256];
    const int t = threadIdx.x;
    const int w = t >> 6, lane = t & 63;
    const int gbase = blockIdx.x * 256 + w * 64;
    const int slot = gbase + lane;
    int myc = -1;
    if (slot < V) {
        int n = order[slot];
        myc = cl[n];
        const float* hr = h + (size_t)n * COUT;
#pragma unroll
        for (int k = 0; k < COUT / 4; ++k)
            *(float4*)&sh[w * 64 + lane][k * 4] = *(const float4*)&hr[k * 4];
        const float* pp = p4 + (size_t)n * 4 + ofs;
        sp[w * 64 + lane][0] = pp[0];
        sp[w * 64 + lane][1] = pp[1];
        sp[w * 64 + lane][2] = pp[2];
    }
    scl2[w * 64 + lane] = myc;
    __syncthreads();

    if (lane < COUT) {
        const int c = lane;
        const int sb = w * 64;
        int prev = scl2[sb];
        float run = 0.f, rp = 0.f;
        for (int i = 0; i < 64; ++i) {
            int cc = scl2[sb + i];
            if (cc != prev) {
                if (prev >= 0) {
                    int en = ioff[prev];
                    int st = en - icnt[prev];
                    if (st >= gbase && en <= gbase + 64) {
                        hp[(size_t)prev * COUT + c] = run;
                        if (c < 3) psum[prev * 3 + c] = rp;
                    } else {
                        atomicMax((int*)&hp[(size_t)prev * COUT + c], __float_as_int(run));
                        if (c < 3) atomicAdd(&psum[prev * 3 + c], rp);
                    }
                }
                prev = cc; run = 0.f; rp = 0.f;
            }
            if (cc >= 0) {
                run = fmaxf(run, sh[sb + i][c]);
                if (c < 3) rp += sp[sb + i][c];
            }
        }
        if (prev >= 0) {
            int en = ioff[prev];
            int st = en - icnt[prev];
            if (st >= gbase && en <= gbase + 64) {
                hp[(size_t)prev * COUT + c] = run;
                if (c < 3) psum[prev * 3 + c] = rp;
            } else {
                atomicMax((int*)&hp[(size_t)prev * COUT + c], __float_as_int(run));
                if (c < 3) atomicAdd(&psum[prev * 3 + c], rp);
            }
        }
    }
}

// ======================= pool finalize (float4 pos outputs) =======================
__global__ __launch_bounds__(256) void finalize_posI_kernel(
    const float* __restrict__ psum, const int* __restrict__ icnt,
    float4* __restrict__ pos_out, int Vc)
{
    int c = blockIdx.x * 256 + threadIdx.x;
    if (c >= Vc) return;
    float m = fmaxf((float)icnt[c], 1.0f);
    pos_out[c] = make_float4(psum[c * 3 + 0] / m, psum[c * 3 + 1] / m,
                             psum[c * 3 + 2] / m, 0.f);
}

__global__ __launch_bounds__(256) void finalize_pos_kernel(
    const float* __restrict__ psum, const float* __restrict__ pcnt,
    float4* __restrict__ pos_out, int Vc)
{
    int c = blockIdx.x * 256 + threadIdx.x;
    if (c >= Vc) return;
    float m = fmaxf(pcnt[c], 1.0f);
    pos_out[c] = make_float4(psum[c * 3 + 0] / m, psum[c * 3 + 1] / m,
                             psum[c * 3 + 2] / m, 0.f);
}

__global__ __launch_bounds__(256) void finalize_mean_kernel(
    const float* __restrict__ hsum, const float* __restrict__ psum,
    const float* __restrict__ pcnt,
    float* __restrict__ hout, float4* __restrict__ pos_out, int Vc)
{
    int g = blockIdx.x * 256 + threadIdx.x;
    if (g >= Vc * 128) return;
    int c = g >> 7, ch = g & 127;
    float m = fmaxf(pcnt[c], 1.0f);
    hout[g] = hsum[g] / m;
    if (ch == 0)
        pos_out[c] = make_float4(psum[c * 3 + 0] / m, psum[c * 3 + 1] / m,
                                 psum[c * 3 + 2] / m, 0.f);
}

// ======================= host =======================
extern "C" void kernel_launch(void* const* d_in, const int* in_sizes, int n_in,
                              void* d_out, int out_size, void* d_ws, size_t ws_size,
                              hipStream_t stream)
{
    (void)in_sizes; (void)n_in; (void)out_size;
    const float* x    = (const float*)d_in[0];
    const float* pos0 = (const float*)d_in[1];
    const int*   bat  = (const int*)d_in[2];
    const int* e1 = (const int*)d_in[3];
    const int* e2 = (const int*)d_in[4];
    const int* e3 = (const int*)d_in[5];
    const int* e4 = (const int*)d_in[6];
    const int* e5 = (const int*)d_in[7];
    const float* W1 = (const float*)d_in[8],  *R1 = (const float*)d_in[9],  *B1 = (const float*)d_in[10];
    const float* W2 = (const float*)d_in[11], *R2 = (const float*)d_in[12], *B2 = (const float*)d_in[13];
    const float* W3 = (const float*)d_in[14], *R3 = (const float*)d_in[15], *B3 = (const float*)d_in[16];
    const float* W4 = (const float*)d_in[17], *R4 = (const float*)d_in[18], *B4 = (const float*)d_in[19];
    const float* W5 = (const float*)d_in[20], *R5 = (const float*)d_in[21], *B5 = (const float*)d_in[22];

    const int E1 = 3600000, E2 = 786432, E3 = 196608, E4 = 24576, E5 = 3072;

    if (ws_size < (size_t)21800000 * sizeof(float)) return;
    float* ws = (float*)d_ws;
    // pools (floats): P0 12.6M | P1 6.3M | P2 1.6M | P3 1.0M ints | P4 0.3M
    float* P0 = ws;
    float* P1 = ws + 12600000;
    float* P2 = ws + 18900000;
    int*   P3 = (int*)(ws + 20500000);
    float* P4 = ws + 21500000;
    int* GCNT   = P3 + 990000;
    int* GCUR   = P3 + 990256;
    int* SCR_BS = P3 + 999744;
    int* SCR_BO = SCR_BS + 96;

    float* out3 = (float*)d_out;           // 1536*128
    float* hfin = (float*)d_out + 196608;  // 192*128

#define MSI(p, ni) hipMemsetAsync((p), 0, (size_t)(ni) * sizeof(int), stream)

#define SCAN(cntp, offp, Vn)                                                                     \
    {                                                                                            \
        int nb_ = ((Vn) + 4095) / 4096;                                                          \
        if (nb_ <= 1) {                                                                          \
            scan1_kernel<<<1, 256, 0, stream>>>((cntp), (offp), nullptr, (Vn));                  \
        } else {                                                                                 \
            scan1_kernel<<<nb_, 256, 0, stream>>>((cntp), (offp), SCR_BS, (Vn));                 \
            scan1_kernel<<<1, 256, 0, stream>>>(SCR_BS, SCR_BO, nullptr, nb_);                   \
            scan_add_kernel<<<((Vn) + 255) / 256, 256, 0, stream>>>((offp), SCR_BO, (Vn));       \
        }                                                                                        \
    }

#define BSORT(cntP, offP, srcP, stP, ep, En, Vn, SHIFT, NB)                                      \
    {                                                                                            \
        MSI(GCNT, 256);                                                                          \
        bin_count_kernel<<<((En) + 4095) / 4096, 256, 0, stream>>>((ep) + (En), GCNT, En, SHIFT);\
        scan1_kernel<<<1, 256, 0, stream>>>(GCNT, GCUR, nullptr, NB);                            \
        bin_scatter_kernel<<<((En) + 4095) / 4096, 256, 0, stream>>>(                            \
            (ep), (ep) + (En), GCUR, stP, En, SHIFT);                                            \
        bucket_csr_kernel<<<NB, 1024, 0, stream>>>(                                              \
            GCUR, GCNT, stP, cntP, offP, srcP, Vn, SHIFT);                                       \
    }

#define ESORT(base, ep, En, Vn)                                                                  \
    int* cnt_ = (base);                                                                          \
    int* off_ = cnt_ + (Vn);                                                                     \
    int* src_ = off_ + (Vn);                                                                     \
    MSI(cnt_, (Vn));                                                                             \
    edge_count_kernel<<<((En) + 255) / 256, 256, 0, stream>>>((ep) + (En), cnt_, En);            \
    SCAN(cnt_, off_, (Vn));                                                                      \
    edge_scatter_kernel<<<8 * (((En) + 1023) / 1024), 256, 0, stream>>>(                         \
        (ep), (ep) + (En), off_, src_, En, (Vn) >> 3)

    // staged pool: counting sort by cluster, then staged segmented reduce.
#define SPOOL(ICLp, IORDp, ICNTp, IOFFp, p4src, ofsv, batp, bdiv, Vn, Vc, NX, NY, NT, COUTV, \
              hsrc, hpool, psumP, posdst)                                                   \
    {                                                                                       \
        MSI(ICNTp, (Vc));                                                                   \
        pool_cluster_kernel<<<((Vn) + 255) / 256, 256, 0, stream>>>(                        \
            p4src, ofsv, batp, bdiv, Vn, NX, NY, NT, ICLp, ICNTp);                          \
        SCAN(ICNTp, IOFFp, (Vc));                                                           \
        pool_scatter_kernel<<<8 * (((Vn) + 1023) / 1024), 256, 0, stream>>>(                \
            ICLp, IOFFp, IORDp, Vn, (Vc) >> 3);                                             \
        MSI(hpool, (size_t)(Vc) * (COUTV));                                                 \
        MSI(psumP, (size_t)(Vc) * 3);                                                       \
        staged_pool_kernel<COUTV><<<((Vn) + 255) / 256, 256, 0, stream>>>(                  \
            IORDp, ICLp, IOFFp, ICNTp, hsrc, p4src, ofsv, hpool, psumP, Vn);                \
        finalize_posI_kernel<<<((Vc) + 255) / 256, 256, 0, stream>>>(                       \
            psumP, ICNTp, (float4*)(posdst), Vc);                                           \
    }

    // ---------- Layer 1: 300000 nodes, CIN=3, COUT=16 -> dense h1; staged pool (64,48,8) --
    {
        int* cnt1 = (int*)P0;
        int* off1 = cnt1 + 300000;
        int* src1 = off1 + 300000;
        int2* st1 = (int2*)(src1 + 3600000);      // 3.6M int2 = 7.2M ints
        float4* xp4 = (float4*)(P0 + 11400000);
        BSORT(cnt1, off1, src1, st1, e1, E1, 300000, 11, 147);
        pack_xpos_kernel<<<(300000 + 255) / 256, 256, 0, stream>>>(x, pos0, xp4, 300000);
        l1_fused_kernel<<<(300000 + 255) / 256, 256, 0, stream>>>(
            off1, cnt1, src1, xp4, W1, R1, B1, P1, 20.0f, 300000);
        // CSR/staging dead (xp4 alive). Pool: ints in P3; hp1->P2; psum1->P0; pos2_4->P0+300000.
        int* ICL1  = P3;
        int* IORD1 = P3 + 300000;
        int* ICNT1 = P3 + 600000;
        int* IOFF1 = P3 + 698304;
        SPOOL(ICL1, IORD1, ICNT1, IOFF1, (const float*)xp4, 1, bat, 0, 300000, 98304,
              64, 48, 8, 16, P1, P2, P0, P0 + 300000);
    }
    float4* pos2_4 = (float4*)(P0 + 300000);     // 98304*4 floats
    // ---------- Layer 2: 98304 nodes, CINF=16, COUT=64 -> dense h2; staged pool (32,24,4) -
    {
        int* cnt2 = P3;
        int* off2 = cnt2 + 98304;
        int* src2 = off2 + 98304;
        int2* st2 = (int2*)(P0 + 1000000);       // staging clear of pos2_4
        BSORT(cnt2, off2, src2, st2, e2, E2, 98304, 10, 96);
        tsum16_layer_kernel<4><<<98304 / 16, 256, 0, stream>>>(
            off2, cnt2, src2, pos2_4, P2, W2, R2, B2, P1, 10.0f, 98304);
        // CSR2 dead -> reuse P3 for pool sort. hp2->P2; psum2->P2+786432; pos3_4->P4.
        int* ICL2  = P3;
        int* IORD2 = P3 + 98304;
        int* ICNT2 = P3 + 196608;
        int* IOFF2 = P3 + 208896;
        SPOOL(ICL2, IORD2, ICNT2, IOFF2, (const float*)pos2_4, 0, nullptr, 24576,
              98304, 12288, 32, 24, 4, 64, P1, P2, P2 + 786432, P4);
    }
    // ---------- Layer 3: 12288 nodes, CINF=64, COUT=128; fused atomic max-pool (16,12,2) --
    {
        ESORT(P3, e3, E3, 12288);
        float* HP3 = P1;                    // 1536*128 = 196608
        float* PS3 = P1 + 196608;           // 1536*3
        float* PC3 = P1 + 201216;           // 1536
        MSI(P1, 202752);
        tsum_layer_kernel<64, 128, 4, 4, 1><<<12288 / 16, 256, 0, stream>>>(
            off_, cnt_, src_, (const float4*)P4, P2, W3, R3, B3, nullptr,
            HP3, PS3, PC3, 6.0f, 12288, 16, 12, 2, 3072);
        finalize_pos_kernel<<<(1536 + 255) / 256, 256, 0, stream>>>(
            PS3, PC3, (float4*)P0, 1536);
    }
    // ---------- Layer 4: 1536 nodes, CINF=128, COUT=128 -> out3; fused mean-pool (8,6,1) --
    {
        ESORT(P3, e4, E4, 1536);
        float* HS4 = P2;                    // 192*128 = 24576 (sums)
        float* PS4 = P2 + 24576;            // 192*3
        float* PC4 = P2 + 25152;            // 192
        MSI(P2, 25344);
        tsum_layer_kernel<128, 128, 2, 4, 2><<<1536 / 8, 256, 0, stream>>>(
            off_, cnt_, src_, (const float4*)P0, P1, W4, R4, B4, out3,
            HS4, PS4, PC4, 3.0f, 1536, 8, 6, 1, 384);
        finalize_mean_kernel<<<(192 * 128 + 255) / 256, 256, 0, stream>>>(
            HS4, PS4, PC4, P1, (float4*)(P0 + 100000), 192);
    }
    // ---------- Layer 5: 192 nodes, CINF=128, COUT=128 -> hfin (no pool) ----------
    {
        ESORT(P3, e5, E5, 192);
        tsum_layer_kernel<128, 128, 2, 4, 0><<<192 / 8, 256, 0, stream>>>(
            off_, cnt_, src_, (const float4*)(P0 + 100000), P1, W5, R5, B5, hfin,
            nullptr, nullptr, nullptr, 1.5f, 192, 1, 1, 1, 1);
    }
#undef SPOOL
#undef ESORT
#undef BSORT
#undef SCAN
#undef MSI
}

// Round 16
// 829.481 us; speedup vs baseline: 1.0493x; 1.0137x over previous
//
#include <hip/hip_runtime.h>
#include <cstdint>

// single-instruction clamp to [0,1]
__device__ __forceinline__ float clamp01f(float v)
{
    return __builtin_amdgcn_fmed3f(v, 0.0f, 1.0f);
}

// factored trilinear basis: 12 mults for the 8 corner weights
__device__ __forceinline__ void basis8(float p0, float p1, float p2, float* bs)
{
    float q0 = 1.f - p0, q1 = 1.f - p1, q2 = 1.f - p2;
    float t00 = q0 * q1, t10 = p0 * q1, t01 = q0 * p1, t11 = p0 * p1;
    bs[0] = t00 * q2; bs[1] = t10 * q2; bs[2] = t01 * q2; bs[3] = t11 * q2;
    bs[4] = t00 * p2; bs[5] = t10 * p2; bs[6] = t01 * p2; bs[7] = t11 * p2;
}

// ======================= legacy CSR build (layers 3-5, small E) =======================
__global__ __launch_bounds__(256) void edge_count_kernel(
    const int* __restrict__ edst, int* __restrict__ cnt, int E)
{
    int e = blockIdx.x * 256 + threadIdx.x;
    if (e < E) atomicAdd(&cnt[__builtin_nontemporal_load(&edst[e])], 1);
}

__global__ __launch_bounds__(256) void edge_scatter_kernel(
    const int* __restrict__ esrc, const int* __restrict__ edst,
    int* __restrict__ off, int* __restrict__ srcs, int E, int rv)
{
    const int lo = (int)(blockIdx.x & 7) * rv;
    const int hi = lo + rv;
    const int base = (int)(blockIdx.x >> 3) << 10;
#pragma unroll
    for (int k = 0; k < 4; ++k) {
        int e = base + (k << 8) + threadIdx.x;
        if (e < E) {
            int d = __builtin_nontemporal_load(&edst[e]);
            if (d >= lo && d < hi) {
                int s = __builtin_nontemporal_load(&esrc[e]);
                int slot = atomicAdd(&off[d], 1);
                srcs[slot] = s;
            }
        }
    }
}

// ============== hierarchical exclusive scan ==============
__global__ __launch_bounds__(256) void scan1_kernel(
    const int* __restrict__ cnt, int* __restrict__ off, int* __restrict__ bsum, int V)
{
    __shared__ int lds[4096];
    __shared__ int ssum[256];
    const int t = threadIdx.x;
    const int base = blockIdx.x * 4096;
    for (int i = t; i < 4096; i += 256) {
        int g = base + i;
        lds[i] = (g < V) ? cnt[g] : 0;
    }
    __syncthreads();
    int loc[16];
    int s = 0;
#pragma unroll
    for (int k = 0; k < 16; ++k) { loc[k] = s; s += lds[t * 16 + k]; }
    ssum[t] = s;
    __syncthreads();
    for (int d = 1; d < 256; d <<= 1) {
        int v = (t >= d) ? ssum[t - d] : 0;
        __syncthreads();
        ssum[t] += v;
        __syncthreads();
    }
    const int tbase = (t == 0) ? 0 : ssum[t - 1];
    if (t == 255 && bsum) bsum[blockIdx.x] = ssum[255];
#pragma unroll
    for (int k = 0; k < 16; ++k) lds[t * 16 + k] = tbase + loc[k];
    __syncthreads();
    for (int i = t; i < 4096; i += 256) {
        int g = base + i;
        if (g < V) off[g] = lds[i];
    }
}

__global__ __launch_bounds__(256) void scan_add_kernel(
    int* __restrict__ off, const int* __restrict__ bso, int V)
{
    int g = blockIdx.x * 256 + threadIdx.x;
    if (g < V) off[g] += bso[g >> 12];
}

// ======================= bucketed CSR build (L1, L2) =======================
__global__ __launch_bounds__(256) void bin_count_kernel(
    const int* __restrict__ edst, int* __restrict__ gcnt, int E, int shift)
{
    __shared__ int h[256];
    const int t = threadIdx.x;
    h[t] = 0;
    __syncthreads();
    const int base = blockIdx.x << 12;
#pragma unroll
    for (int k = 0; k < 16; ++k) {
        int e = base + (k << 8) + t;
        if (e < E) {
            int d = __builtin_nontemporal_load(&edst[e]);
            atomicAdd(&h[d >> shift], 1);
        }
    }
    __syncthreads();
    if (h[t]) atomicAdd(&gcnt[t], h[t]);
}

// staging packed as int2 (dst, src): one 8B store per edge, paired locality on read.
__global__ __launch_bounds__(256) void bin_scatter_kernel(
    const int* __restrict__ esrc, const int* __restrict__ edst,
    int* __restrict__ gcur, int2* __restrict__ st, int E, int shift)
{
    __shared__ int d_l[4096];
    __shared__ int s_l[4096];
    __shared__ int h[256];
    __shared__ int rbase[256];
    const int t = threadIdx.x;
    h[t] = 0;
    __syncthreads();
    const int base = blockIdx.x << 12;
#pragma unroll
    for (int k = 0; k < 16; ++k) {
        int i = (k << 8) + t;
        int e = base + i;
        if (e < E) {
            int d = __builtin_nontemporal_load(&edst[e]);
            int s = __builtin_nontemporal_load(&esrc[e]);
            d_l[i] = d; s_l[i] = s;
            atomicAdd(&h[d >> shift], 1);
        }
    }
    __syncthreads();
    rbase[t] = h[t] ? atomicAdd(&gcur[t], h[t]) : 0;
    h[t] = 0;   // reuse as cursor
    __syncthreads();
#pragma unroll
    for (int k = 0; k < 16; ++k) {
        int i = (k << 8) + t;
        int e = base + i;
        if (e < E) {
            int d = d_l[i];
            int b = d >> shift;
            int r = atomicAdd(&h[b], 1);
            st[rbase[b] + r] = make_int2(d, s_l[i]);
        }
    }
}

__global__ __launch_bounds__(1024) void bucket_csr_kernel(
    const int* __restrict__ gcur, const int* __restrict__ gcnt,
    const int2* __restrict__ st,
    int* __restrict__ cnt, int* __restrict__ off, int* __restrict__ srcs,
    int V, int shift)
{
    __shared__ int h[2048];
    __shared__ int o[2048];
    __shared__ int ps[1024];
    const int t = threadIdx.x;
    const int b = blockIdx.x;
    const int v0 = b << shift;
    const int nv = min(1 << shift, V - v0);
    const int s1 = gcur[b];
    const int s0 = s1 - gcnt[b];
    h[t] = 0; h[t + 1024] = 0;
    __syncthreads();
    for (int i = s0 + t; i < s1; i += 1024)
        atomicAdd(&h[st[i].x - v0], 1);
    __syncthreads();
    int a = h[2 * t], b2 = h[2 * t + 1];
    ps[t] = a + b2;
    __syncthreads();
    for (int d = 1; d < 1024; d <<= 1) {
        int v = (t >= d) ? ps[t - d] : 0;
        __syncthreads();
        ps[t] += v;
        __syncthreads();
    }
    int pb = (t == 0) ? 0 : ps[t - 1];
    o[2 * t] = pb;
    o[2 * t + 1] = pb + a;
    __syncthreads();
    for (int i = t; i < nv; i += 1024) {
        int hv = h[i];
        cnt[v0 + i] = hv;
        off[v0 + i] = s0 + o[i] + hv;   // segment END convention
    }
    __syncthreads();
    for (int i = s0 + t; i < s1; i += 1024) {
        int2 e = st[i];
        int r = atomicAdd(&o[e.x - v0], 1);
        srcs[s0 + r] = e.y;
    }
}

// ======================= pack (x, pos) into float4 for layer-1 gathers =======
__global__ __launch_bounds__(256) void pack_xpos_kernel(
    const float* __restrict__ x, const float* __restrict__ pos,
    float4* __restrict__ xp, int V)
{
    int n = blockIdx.x * 256 + threadIdx.x;
    if (n >= V) return;
    xp[n] = make_float4(x[n], pos[n * 3 + 0], pos[n * 3 + 1], pos[n * 3 + 2]);
}

// ========== Layer-1 fused, tsum, DENSE output; fused cluster-id epilogue ==========
// One FMA per dim per edge: p = fma(-inv2mv, pa, pd') with pd' = pd*inv2mv + 0.5.
__device__ __forceinline__ void l1_edge_acc(
    float dx_, float dy_, float dz_, const float4 a, float inv2mv, float ts[8][3])
{
    float p0 = clamp01f(fmaf(-inv2mv, a.y, dx_));
    float p1 = clamp01f(fmaf(-inv2mv, a.z, dy_));
    float p2 = clamp01f(fmaf(-inv2mv, a.w, dz_));
    float bs[8];
    basis8(p0, p1, p2, bs);
#pragma unroll
    for (int s8 = 0; s8 < 8; ++s8) {
        ts[s8][0] += bs[s8] * a.x;
        ts[s8][1] += bs[s8] * a.y;
        ts[s8][2] += bs[s8] * a.z;
    }
}

__global__ __launch_bounds__(256) void l1_fused_kernel(
    const int* __restrict__ off, const int* __restrict__ cnt, const int* __restrict__ srcs,
    const float4* __restrict__ xp, const int* __restrict__ bat,
    const float* __restrict__ Wk, const float* __restrict__ Wr,
    const float* __restrict__ bias, float* __restrict__ out,
    int* __restrict__ icl, int* __restrict__ icnt,
    float inv2mv, int V)
{
    __shared__ float sWk[384];
    __shared__ float sWr[48];
    __shared__ float sB[16];
    const int t = threadIdx.x;
    for (int i = t; i < 384; i += 256) sWk[i] = Wk[i];
    if (t < 48) sWr[t] = Wr[t];
    if (t < 16) sB[t] = bias[t];
    __syncthreads();
    const int v = blockIdx.x * 256 + t;
    if (v >= V) return;
    const float4 d = xp[v];  // x, px, py, pt
    const float dx_ = fmaf(d.y, inv2mv, 0.5f);
    const float dy_ = fmaf(d.z, inv2mv, 0.5f);
    const float dz_ = fmaf(d.w, inv2mv, 0.5f);
    const int e1 = off[v];
    const int n = cnt[v];
    float ts[8][3];
#pragma unroll
    for (int s8 = 0; s8 < 8; ++s8) { ts[s8][0] = 0.f; ts[s8][1] = 0.f; ts[s8][2] = 0.f; }
    int j = e1 - n;
    for (; j + 3 < e1; j += 4) {
        float4 a0 = xp[srcs[j]];
        float4 a1 = xp[srcs[j + 1]];
        float4 a2 = xp[srcs[j + 2]];
        float4 a3 = xp[srcs[j + 3]];
        l1_edge_acc(dx_, dy_, dz_, a0, inv2mv, ts);
        l1_edge_acc(dx_, dy_, dz_, a1, inv2mv, ts);
        l1_edge_acc(dx_, dy_, dz_, a2, inv2mv, ts);
        l1_edge_acc(dx_, dy_, dz_, a3, inv2mv, ts);
    }
    for (; j < e1; ++j)
        l1_edge_acc(dx_, dy_, dz_, xp[srcs[j]], inv2mv, ts);
    const float invn = 1.0f / fmaxf((float)n, 1.0f);
    float rr[16];
#pragma unroll
    for (int c = 0; c < 16; ++c) {
        float m = 0.f;
#pragma unroll
        for (int s8 = 0; s8 < 8; ++s8)
            m += ts[s8][0] * sWk[s8 * 48 + c]
               + ts[s8][1] * sWk[s8 * 48 + 16 + c]
               + ts[s8][2] * sWk[s8 * 48 + 32 + c];
        float r = m * invn + d.x * sWr[c] + d.y * sWr[16 + c] + d.z * sWr[32 + c] + sB[c];
        rr[c] = fmaxf(r, 0.0f);
    }
    float4* op = (float4*)(out + (size_t)v * 16);
#pragma unroll
    for (int k = 0; k < 4; ++k)
        op[k] = make_float4(rr[4 * k], rr[4 * k + 1], rr[4 * k + 2], rr[4 * k + 3]);
    // fused pool-cluster (grid 64,48,8)
    int bb = bat[v];
    int ix = min(max((int)floorf(d.y * 64.f), 0), 63);
    int iy = min(max((int)floorf(d.z * 48.f), 0), 47);
    int it = min(max((int)floorf(d.w * 8.f), 0), 7);
    int cl = ((bb * 64 + ix) * 48 + iy) * 8 + it;
    icl[v] = cl;
    atomicAdd(&icnt[cl], 1);
}

// ========== Layer-2 tsum, quarter-wave-per-node; fused cluster-id epilogue ==========
__device__ __forceinline__ void l2_edge_acc(
    float dx_, float dy_, float dz_, const float4 pa, float fa, int l16, float inv2mv,
    float* accF, float* accP)
{
    float p0 = clamp01f(fmaf(-inv2mv, pa.x, dx_));
    float p1 = clamp01f(fmaf(-inv2mv, pa.y, dy_));
    float p2 = clamp01f(fmaf(-inv2mv, pa.z, dz_));
    float bs[8];
    basis8(p0, p1, p2, bs);
    const float fp = (l16 == 0) ? pa.x : ((l16 == 1) ? pa.y : 0.f);
#pragma unroll
    for (int s8 = 0; s8 < 8; ++s8) {
        accF[s8] += bs[s8] * fa;
        accP[s8] += bs[s8] * fp;
    }
}

template<int NW>
__global__ __launch_bounds__(64 * NW) void tsum16_layer_kernel(
    const int* __restrict__ off, const int* __restrict__ cnt, const int* __restrict__ srcs,
    const float4* __restrict__ pos4, const float* __restrict__ feat,
    const float* __restrict__ Wk, const float* __restrict__ Wr,
    const float* __restrict__ bias, float* __restrict__ out,
    int* __restrict__ icl, int* __restrict__ icnt,
    float inv2mv, int V)
{
    __shared__ float tsum[NW][4][18][9];
    const int tid = threadIdx.x;
    const int w = tid >> 6, lane = tid & 63;
    const int q = lane >> 4, l16 = lane & 15;
    const int vbase = (blockIdx.x * NW + w) * 4;
    const int v = vbase + q;        // V divisible by 4*NW -> always < V

    const float4 pd = pos4[v];
    const float dx_ = fmaf(pd.x, inv2mv, 0.5f);
    const float dy_ = fmaf(pd.y, inv2mv, 0.5f);
    const float dz_ = fmaf(pd.z, inv2mv, 0.5f);
    const int e1 = off[v];
    const int n = cnt[v];
    float accF[8], accP[8];
#pragma unroll
    for (int s8 = 0; s8 < 8; ++s8) { accF[s8] = 0.f; accP[s8] = 0.f; }
    int j = e1 - n;
    for (; j + 3 < e1; j += 4) {
        const int s0 = srcs[j], s1 = srcs[j + 1], s2 = srcs[j + 2], s3 = srcs[j + 3];
        const float4 pa = pos4[s0];
        const float4 pb = pos4[s1];
        const float4 pc = pos4[s2];
        const float4 pe = pos4[s3];
        const float fa = feat[s0 * 16 + l16];
        const float fb = feat[s1 * 16 + l16];
        const float fc = feat[s2 * 16 + l16];
        const float fe = feat[s3 * 16 + l16];
        l2_edge_acc(dx_, dy_, dz_, pa, fa, l16, inv2mv, accF, accP);
        l2_edge_acc(dx_, dy_, dz_, pb, fb, l16, inv2mv, accF, accP);
        l2_edge_acc(dx_, dy_, dz_, pc, fc, l16, inv2mv, accF, accP);
        l2_edge_acc(dx_, dy_, dz_, pe, fe, l16, inv2mv, accF, accP);
    }
    for (; j < e1; ++j) {
        const int s = srcs[j];
        const float4 pa = pos4[s];
        const float fa = feat[s * 16 + l16];
        l2_edge_acc(dx_, dy_, dz_, pa, fa, l16, inv2mv, accF, accP);
    }
#pragma unroll
    for (int s8 = 0; s8 < 8; ++s8)
        tsum[w][q][l16][s8] = accF[s8];
    tsum[w][q][l16][8] = feat[v * 16 + l16];
    if (l16 < 2) {
#pragma unroll
        for (int s8 = 0; s8 < 8; ++s8)
            tsum[w][q][16 + l16][s8] = accP[s8];
        tsum[w][q][16 + l16][8] = (l16 == 0) ? pd.x : pd.y;
    }
    if (l16 == 0) {     // fused pool-cluster (grid 32,24,4)
        int bb = v / 24576;
        int ix = min(max((int)floorf(pd.x * 32.f), 0), 31);
        int iy = min(max((int)floorf(pd.y * 24.f), 0), 23);
        int it = min(max((int)floorf(pd.z * 4.f), 0), 3);
        int cl = ((bb * 32 + ix) * 24 + iy) * 4 + it;
        icl[v] = cl;
        atomicAdd(&icnt[cl], 1);
    }
    __syncthreads();

    float oA[4], oR[4];
#pragma unroll
    for (int b = 0; b < 4; ++b) { oA[b] = 0.f; oR[b] = 0.f; }
    for (int s8 = 0; s8 < 8; ++s8) {
        const float* W = Wk + (size_t)s8 * 18 * 64;
        for (int ci = 0; ci < 18; ++ci) {
            float wv = W[ci * 64 + lane];
#pragma unroll
            for (int b = 0; b < 4; ++b)
                oA[b] += tsum[w][b][ci][s8] * wv;
        }
    }
    for (int ci = 0; ci < 18; ++ci) {
        float wv = Wr[ci * 64 + lane];
#pragma unroll
        for (int b = 0; b < 4; ++b)
            oR[b] += tsum[w][b][ci][8] * wv;
    }
    const float bi = bias[lane];
#pragma unroll
    for (int b = 0; b < 4; ++b) {
        int vv = vbase + b;
        float invn = 1.0f / fmaxf((float)cnt[vv], 1.0f);
        out[(size_t)vv * 64 + lane] = fmaxf(oA[b] * invn + oR[b] + bi, 0.0f);
    }
}

// ========== Generic tsum layer (L3-5), 2-edge unroll, fused pooling ==========
// PMODE: 0 = dense out only (L5), 1 = atomic max-pool only (L3),
//        2 = dense out + atomic mean-pool sums (L4).
template<int CINF, int COUT, int NV, int NW, int PMODE>
__global__ __launch_bounds__(64 * NW) void tsum_layer_kernel(
    const int* __restrict__ off, const int* __restrict__ cnt, const int* __restrict__ srcs,
    const float4* __restrict__ pos4, const float* __restrict__ feat,
    const float* __restrict__ Wk, const float* __restrict__ Wr,
    const float* __restrict__ bias, float* __restrict__ out,
    float* __restrict__ hp, float* __restrict__ psum, float* __restrict__ pcnt,
    float inv2mv, int V, int gx, int gy, int gt, int bdiv)
{
    constexpr int CIN = CINF + 2;
    constexpr int NCI = (CIN + 63) / 64;
    constexpr int NCC = COUT / 64;
    __shared__ float tsum[NW][NV][CIN][9];
    __shared__ int scl[NW][NV];
    const int tid = threadIdx.x;
    const int w = tid >> 6, lane = tid & 63;
    const int vbase = (blockIdx.x * NW + w) * NV;

    for (int b = 0; b < NV; ++b) {
        const int v = vbase + b;
        if (v >= V) break;
        const float4 pd = pos4[v];
        const float dx_ = fmaf(pd.x, inv2mv, 0.5f);
        const float dy_ = fmaf(pd.y, inv2mv, 0.5f);
        const float dz_ = fmaf(pd.z, inv2mv, 0.5f);
        float acc[NCI][8];
#pragma unroll
        for (int k = 0; k < NCI; ++k)
#pragma unroll
            for (int s8 = 0; s8 < 8; ++s8) acc[k][s8] = 0.f;
        const int e1 = off[v];
        int j = e1 - cnt[v];
        for (; j + 1 < e1; j += 2) {
            const int s0 = srcs[j], s1 = srcs[j + 1];
            const float4 pa = pos4[s0];
            const float4 pb = pos4[s1];
            float fa[NCI], fb[NCI];
#pragma unroll
            for (int k = 0; k < NCI; ++k) {
                int ci = lane + 64 * k;
                fa[k] = (ci < CINF) ? feat[s0 * CINF + ci]
                       : (ci == CINF ? pa.x : (ci == CINF + 1 ? pa.y : 0.f));
                fb[k] = (ci < CINF) ? feat[s1 * CINF + ci]
                       : (ci == CINF ? pb.x : (ci == CINF + 1 ? pb.y : 0.f));
            }
            float pa0 = clamp01f(fmaf(-inv2mv, pa.x, dx_));
            float pa1 = clamp01f(fmaf(-inv2mv, pa.y, dy_));
            float pa2 = clamp01f(fmaf(-inv2mv, pa.z, dz_));
            float pb0 = clamp01f(fmaf(-inv2mv, pb.x, dx_));
            float pb1 = clamp01f(fmaf(-inv2mv, pb.y, dy_));
            float pb2 = clamp01f(fmaf(-inv2mv, pb.z, dz_));
            float ba[8], bb[8];
            basis8(pa0, pa1, pa2, ba);
            basis8(pb0, pb1, pb2, bb);
#pragma unroll
            for (int s8 = 0; s8 < 8; ++s8)
#pragma unroll
                for (int k = 0; k < NCI; ++k)
                    acc[k][s8] += ba[s8] * fa[k] + bb[s8] * fb[k];
        }
        if (j < e1) {
            const int s = srcs[j];
            const float4 pa = pos4[s];
            float fa[NCI];
#pragma unroll
            for (int k = 0; k < NCI; ++k) {
                int ci = lane + 64 * k;
                fa[k] = (ci < CINF) ? feat[s * CINF + ci]
                       : (ci == CINF ? pa.x : (ci == CINF + 1 ? pa.y : 0.f));
            }
            float p0 = clamp01f(fmaf(-inv2mv, pa.x, dx_));
            float p1 = clamp01f(fmaf(-inv2mv, pa.y, dy_));
            float p2 = clamp01f(fmaf(-inv2mv, pa.z, dz_));
            float bs[8];
            basis8(p0, p1, p2, bs);
#pragma unroll
            for (int s8 = 0; s8 < 8; ++s8)
#pragma unroll
                for (int k = 0; k < NCI; ++k)
                    acc[k][s8] += bs[s8] * fa[k];
        }
#pragma unroll
        for (int k = 0; k < NCI; ++k) {
            int ci = lane + 64 * k;
            if (ci < CIN) {
#pragma unroll
                for (int s8 = 0; s8 < 8; ++s8)
                    tsum[w][b][ci][s8] = acc[k][s8];
                tsum[w][b][ci][8] = (ci < CINF) ? feat[v * CINF + ci]
                                                : (ci == CINF ? pd.x : pd.y);
            }
        }
        if (PMODE != 0 && lane == 0) {
            int bb2 = v / bdiv;
            int ix = min(max((int)floorf(pd.x * (float)gx), 0), gx - 1);
            int iy = min(max((int)floorf(pd.y * (float)gy), 0), gy - 1);
            int it = min(max((int)floorf(pd.z * (float)gt), 0), gt - 1);
            int cl = ((bb2 * gx + ix) * gy + iy) * gt + it;
            scl[w][b] = cl;
            atomicAdd(&psum[cl * 3 + 0], pd.x);
            atomicAdd(&psum[cl * 3 + 1], pd.y);
            atomicAdd(&psum[cl * 3 + 2], pd.z);
            atomicAdd(&pcnt[cl], 1.0f);
        }
    }
    __syncthreads();

    float oA[NV][NCC], oR[NV][NCC];
#pragma unroll
    for (int b = 0; b < NV; ++b)
#pragma unroll
        for (int cc = 0; cc < NCC; ++cc) { oA[b][cc] = 0.f; oR[b][cc] = 0.f; }
    for (int s8 = 0; s8 < 8; ++s8) {
        const float* W = Wk + (size_t)s8 * CIN * COUT;
        for (int ci = 0; ci < CIN; ++ci) {
            float wv[NCC];
#pragma unroll
            for (int cc = 0; cc < NCC; ++cc)
                wv[cc] = W[(size_t)ci * COUT + cc * 64 + lane];
#pragma unroll
            for (int b = 0; b < NV; ++b) {
                float tv = tsum[w][b][ci][s8];
#pragma unroll
                for (int cc = 0; cc < NCC; ++cc) oA[b][cc] += tv * wv[cc];
            }
        }
    }
    for (int ci = 0; ci < CIN; ++ci) {
        float wv[NCC];
#pragma unroll
        for (int cc = 0; cc < NCC; ++cc)
            wv[cc] = Wr[(size_t)ci * COUT + cc * 64 + lane];
#pragma unroll
        for (int b = 0; b < NV; ++b) {
            float tv = tsum[w][b][ci][8];
#pragma unroll
            for (int cc = 0; cc < NCC; ++cc) oR[b][cc] += tv * wv[cc];
        }
    }
    for (int b = 0; b < NV; ++b) {
        int v = vbase + b;
        if (v >= V) break;
        float invn = 1.0f / fmaxf((float)cnt[v], 1.0f);
#pragma unroll
        for (int cc = 0; cc < NCC; ++cc) {
            int c = cc * 64 + lane;
            float val = fmaxf(oA[b][cc] * invn + oR[b][cc] + bias[c], 0.0f);
            if (PMODE == 0 || PMODE == 2)
                out[(size_t)v * COUT + c] = val;
            if (PMODE == 1)
                atomicMax((int*)&hp[(size_t)scl[w][b] * COUT + c], __float_as_int(val));
            if (PMODE == 2)
                atomicAdd(&hp[(size_t)scl[w][b] * COUT + c], val);
        }
    }
}

// ======================= voxel pooling: scatter + staged reduce =======================
__global__ __launch_bounds__(256) void pool_scatter_kernel(
    const int* __restrict__ cl, int* __restrict__ off, int* __restrict__ order, int V, int rv)
{
    const int lo = (int)(blockIdx.x & 7) * rv;
    const int hi = lo + rv;
    const int base = (int)(blockIdx.x >> 3) << 10;
#pragma unroll
    for (int k = 0; k < 4; ++k) {
        int n = base + (k << 8) + threadIdx.x;
        if (n < V) {
            int c = __builtin_nontemporal_load(&cl[n]);
            if (c >= lo && c < hi) {
                int slot = atomicAdd(&off[c], 1);
                order[slot] = n;
            }
        }
    }
}

// ========= staged segmented max-pool: wave owns 64 sorted slots ===============
template<int COUT>
__global__ __launch_bounds__(256) void staged_pool_kernel(
    const int* __restrict__ order, const int* __restrict__ cl,
    const int* __restrict__ ioff, const int* __restrict__ icnt,
    const float* __restrict__ h, const float* __restrict__ p4, int ofs,
    float* __restrict__ hp, float* __restrict__ psum, int V)
{
    __shared__ float sh[256][COUT + 4];
    __shared__ float sp[256][3];
    __shared__ int scl2[256];
    const int t = threadIdx.x;
    const int w = t >> 6, lane = t & 63;
    const int gbase = blockIdx.x * 256 + w * 64;
    const int slot = gbase + lane;
    int myc = -1;
    if (slot < V) {
        int n = order[slot];
        myc = cl[n];
        const float* hr = h + (size_t)n * COUT;
#pragma unroll
        for (int k = 0; k < COUT / 4; ++k)
            *(float4*)&sh[w * 64 + lane][k * 4] = *(const float4*)&hr[k * 4];
        const float* pp = p4 + (size_t)n * 4 + ofs;
        sp[w * 64 + lane][0] = pp[0];
        sp[w * 64 + lane][1] = pp[1];
        sp[w * 64 + lane][2] = pp[2];
    }
    scl2[w * 64 + lane] = myc;
    __syncthreads();

    if (lane < COUT) {
        const int c = lane;
        const int sb = w * 64;
        int prev = scl2[sb];
        float run = 0.f, rp = 0.f;
        for (int i = 0; i < 64; ++i) {
            int cc = scl2[sb + i];
            if (cc != prev) {
                if (prev >= 0) {
                    int en = ioff[prev];
                    int st = en - icnt[prev];
                    if (st >= gbase && en <= gbase + 64) {
                        hp[(size_t)prev * COUT + c] = run;
                        if (c < 3) psum[prev * 3 + c] = rp;
                    } else {
                        atomicMax((int*)&hp[(size_t)prev * COUT + c], __float_as_int(run));
                        if (c < 3) atomicAdd(&psum[prev * 3 + c], rp);
                    }
                }
                prev = cc; run = 0.f; rp = 0.f;
            }
            if (cc >= 0) {
                run = fmaxf(run, sh[sb + i][c]);
                if (c < 3) rp += sp[sb + i][c];
            }
        }
        if (prev >= 0) {
            int en = ioff[prev];
            int st = en - icnt[prev];
            if (st >= gbase && en <= gbase + 64) {
                hp[(size_t)prev * COUT + c] = run;
                if (c < 3) psum[prev * 3 + c] = rp;
            } else {
                atomicMax((int*)&hp[(size_t)prev * COUT + c], __float_as_int(run));
                if (c < 3) atomicAdd(&psum[prev * 3 + c], rp);
            }
        }
    }
}

// ======================= pool finalize (float4 pos outputs) =======================
__global__ __launch_bounds__(256) void finalize_posI_kernel(
    const float* __restrict__ psum, const int* __restrict__ icnt,
    float4* __restrict__ pos_out, int Vc)
{
    int c = blockIdx.x * 256 + threadIdx.x;
    if (c >= Vc) return;
    float m = fmaxf((float)icnt[c], 1.0f);
    pos_out[c] = make_float4(psum[c * 3 + 0] / m, psum[c * 3 + 1] / m,
                             psum[c * 3 + 2] / m, 0.f);
}

__global__ __launch_bounds__(256) void finalize_pos_kernel(
    const float* __restrict__ psum, const float* __restrict__ pcnt,
    float4* __restrict__ pos_out, int Vc)
{
    int c = blockIdx.x * 256 + threadIdx.x;
    if (c >= Vc) return;
    float m = fmaxf(pcnt[c], 1.0f);
    pos_out[c] = make_float4(psum[c * 3 + 0] / m, psum[c * 3 + 1] / m,
                             psum[c * 3 + 2] / m, 0.f);
}

__global__ __launch_bounds__(256) void finalize_mean_kernel(
    const float* __restrict__ hsum, const float* __restrict__ psum,
    const float* __restrict__ pcnt,
    float* __restrict__ hout, float4* __restrict__ pos_out, int Vc)
{
    int g = blockIdx.x * 256 + threadIdx.x;
    if (g >= Vc * 128) return;
    int c = g >> 7, ch = g & 127;
    float m = fmaxf(pcnt[c], 1.0f);
    hout[g] = hsum[g] / m;
    if (ch == 0)
        pos_out[c] = make_float4(psum[c * 3 + 0] / m, psum[c * 3 + 1] / m,
                                 psum[c * 3 + 2] / m, 0.f);
}

// ======================= host =======================
extern "C" void kernel_launch(void* const* d_in, const int* in_sizes, int n_in,
                              void* d_out, int out_size, void* d_ws, size_t ws_size,
                              hipStream_t stream)
{
    (void)in_sizes; (void)n_in; (void)out_size;
    const float* x    = (const float*)d_in[0];
    const float* pos0 = (const float*)d_in[1];
    const int*   bat  = (const int*)d_in[2];
    const int* e1 = (const int*)d_in[3];
    const int* e2 = (const int*)d_in[4];
    const int* e3 = (const int*)d_in[5];
    const int* e4 = (const int*)d_in[6];
    const int* e5 = (const int*)d_in[7];
    const float* W1 = (const float*)d_in[8],  *R1 = (const float*)d_in[9],  *B1 = (const float*)d_in[10];
    const float* W2 = (const float*)d_in[11], *R2 = (const float*)d_in[12], *B2 = (const float*)d_in[13];
    const float* W3 = (const float*)d_in[14], *R3 = (const float*)d_in[15], *B3 = (const float*)d_in[16];
    const float* W4 = (const float*)d_in[17], *R4 = (const float*)d_in[18], *B4 = (const float*)d_in[19];
    const float* W5 = (const float*)d_in[20], *R5 = (const float*)d_in[21], *B5 = (const float*)d_in[22];

    const int E1 = 3600000, E2 = 786432, E3 = 196608, E4 = 24576, E5 = 3072;

    if (ws_size < (size_t)21800000 * sizeof(float)) return;
    float* ws = (float*)d_ws;
    // pools (floats): P0 12.6M | P1 6.3M | P2 1.6M | P3 1.0M ints | P4 0.3M
    float* P0 = ws;
    float* P1 = ws + 12600000;
    float* P2 = ws + 18900000;
    int*   P3 = (int*)(ws + 20500000);
    float* P4 = ws + 21500000;
    int* GCNT   = P3 + 990000;
    int* GCUR   = P3 + 990256;
    int* SCR_BS = P3 + 999744;
    int* SCR_BO = SCR_BS + 96;

    float* out3 = (float*)d_out;           // 1536*128
    float* hfin = (float*)d_out + 196608;  // 192*128

#define MSI(p, ni) hipMemsetAsync((p), 0, (size_t)(ni) * sizeof(int), stream)

#define SCAN(cntp, offp, Vn)                                                                     \
    {                                                                                            \
        int nb_ = ((Vn) + 4095) / 4096;                                                          \
        if (nb_ <= 1) {                                                                          \
            scan1_kernel<<<1, 256, 0, stream>>>((cntp), (offp), nullptr, (Vn));                  \
        } else {                                                                                 \
            scan1_kernel<<<nb_, 256, 0, stream>>>((cntp), (offp), SCR_BS, (Vn));                 \
            scan1_kernel<<<1, 256, 0, stream>>>(SCR_BS, SCR_BO, nullptr, nb_);                   \
            scan_add_kernel<<<((Vn) + 255) / 256, 256, 0, stream>>>((offp), SCR_BO, (Vn));       \
        }                                                                                        \
    }

#define BSORT(cntP, offP, srcP, stP, ep, En, Vn, SHIFT, NB)                                      \
    {                                                                                            \
        MSI(GCNT, 256);                                                                          \
        bin_count_kernel<<<((En) + 4095) / 4096, 256, 0, stream>>>((ep) + (En), GCNT, En, SHIFT);\
        scan1_kernel<<<1, 256, 0, stream>>>(GCNT, GCUR, nullptr, NB);                            \
        bin_scatter_kernel<<<((En) + 4095) / 4096, 256, 0, stream>>>(                            \
            (ep), (ep) + (En), GCUR, stP, En, SHIFT);                                            \
        bucket_csr_kernel<<<NB, 1024, 0, stream>>>(                                              \
            GCUR, GCNT, stP, cntP, offP, srcP, Vn, SHIFT);                                       \
    }

#define ESORT(base, ep, En, Vn)                                                                  \
    int* cnt_ = (base);                                                                          \
    int* off_ = cnt_ + (Vn);                                                                     \
    int* src_ = off_ + (Vn);                                                                     \
    MSI(cnt_, (Vn));                                                                             \
    edge_count_kernel<<<((En) + 255) / 256, 256, 0, stream>>>((ep) + (En), cnt_, En);            \
    SCAN(cnt_, off_, (Vn));                                                                      \
    edge_scatter_kernel<<<8 * (((En) + 1023) / 1024), 256, 0, stream>>>(                         \
        (ep), (ep) + (En), off_, src_, En, (Vn) >> 3)

    // staged pool WITHOUT cluster kernel (cl/cnt produced by the layer's epilogue).
#define SPOOL2(ICLp, IORDp, ICNTp, IOFFp, p4src, ofsv, Vn, Vc, COUTV, hsrc, hpool, psumP, posdst) \
    {                                                                                       \
        SCAN(ICNTp, IOFFp, (Vc));                                                           \
        pool_scatter_kernel<<<8 * (((Vn) + 1023) / 1024), 256, 0, stream>>>(                \
            ICLp, IOFFp, IORDp, Vn, (Vc) >> 3);                                             \
        MSI(hpool, (size_t)(Vc) * (COUTV));                                                 \
        MSI(psumP, (size_t)(Vc) * 3);                                                       \
        staged_pool_kernel<COUTV><<<((Vn) + 255) / 256, 256, 0, stream>>>(                  \
            IORDp, ICLp, IOFFp, ICNTp, hsrc, p4src, ofsv, hpool, psumP, Vn);                \
        finalize_posI_kernel<<<((Vc) + 255) / 256, 256, 0, stream>>>(                       \
            psumP, ICNTp, (float4*)(posdst), Vc);                                           \
    }

    // ---------- Layer 1: 300000 nodes, CIN=3, COUT=16 -> dense h1; staged pool (64,48,8) --
    {
        int* cnt1 = (int*)P0;
        int* off1 = cnt1 + 300000;
        int* src1 = off1 + 300000;
        int2* st1 = (int2*)(src1 + 3600000);      // 3.6M int2 = 7.2M ints
        float4* xp4 = (float4*)(P0 + 11400000);
        int* ICL1  = P3;
        int* IORD1 = P3 + 300000;
        int* ICNT1 = P3 + 600000;
        int* IOFF1 = P3 + 698304;
        BSORT(cnt1, off1, src1, st1, e1, E1, 300000, 11, 147);
        pack_xpos_kernel<<<(300000 + 255) / 256, 256, 0, stream>>>(x, pos0, xp4, 300000);
        MSI(ICNT1, 98304);
        l1_fused_kernel<<<(300000 + 255) / 256, 256, 0, stream>>>(
            off1, cnt1, src1, xp4, bat, W1, R1, B1, P1, ICL1, ICNT1, 20.0f, 300000);
        // CSR/staging dead (xp4 alive). hp1->P2; psum1->P0; pos2_4->P0+300000.
        SPOOL2(ICL1, IORD1, ICNT1, IOFF1, (const float*)xp4, 1, 300000, 98304,
               16, P1, P2, P0, P0 + 300000);
    }
    float4* pos2_4 = (float4*)(P0 + 300000);     // 98304*4 floats
    // ---------- Layer 2: 98304 nodes, CINF=16, COUT=64 -> dense h2; staged pool (32,24,4) -
    {
        int* cnt2 = P3;
        int* off2 = cnt2 + 98304;
        int* src2 = off2 + 98304;
        int2* st2 = (int2*)(P0 + 1000000);       // staging clear of pos2_4
        BSORT(cnt2, off2, src2, st2, e2, E2, 98304, 10, 96);
        // pool scratch in the (now dead) staging region — CSR in P3 stays live for tsum16
        int* ICL2  = (int*)(P0 + 1000000);
        int* ICNT2 = ICL2 + 98304;
        int* IORD2 = ICNT2 + 12288;
        int* IOFF2 = IORD2 + 98304;
        MSI(ICNT2, 12288);
        tsum16_layer_kernel<4><<<98304 / 16, 256, 0, stream>>>(
            off2, cnt2, src2, pos2_4, P2, W2, R2, B2, P1, ICL2, ICNT2, 10.0f, 98304);
        // hp2->P2; psum2->P2+786432; pos3_4->P4.
        SPOOL2(ICL2, IORD2, ICNT2, IOFF2, (const float*)pos2_4, 0, 98304, 12288,
               64, P1, P2, P2 + 786432, P4);
    }
    // ---------- Layer 3: 12288 nodes, CINF=64, COUT=128; fused atomic max-pool (16,12,2) --
    {
        ESORT(P3, e3, E3, 12288);
        float* HP3 = P1;                    // 1536*128 = 196608
        float* PS3 = P1 + 196608;           // 1536*3
        float* PC3 = P1 + 201216;           // 1536
        MSI(P1, 202752);
        tsum_layer_kernel<64, 128, 4, 4, 1><<<12288 / 16, 256, 0, stream>>>(
            off_, cnt_, src_, (const float4*)P4, P2, W3, R3, B3, nullptr,
            HP3, PS3, PC3, 6.0f, 12288, 16, 12, 2, 3072);
        finalize_pos_kernel<<<(1536 + 255) / 256, 256, 0, stream>>>(
            PS3, PC3, (float4*)P0, 1536);
    }
    // ---------- Layer 4: 1536 nodes, CINF=128, COUT=128 -> out3; fused mean-pool (8,6,1) --
    {
        ESORT(P3, e4, E4, 1536);
        float* HS4 = P2;                    // 192*128 = 24576 (sums)
        float* PS4 = P2 + 24576;            // 192*3
        float* PC4 = P2 + 25152;            // 192
        MSI(P2, 25344);
        tsum_layer_kernel<128, 128, 2, 4, 2><<<1536 / 8, 256, 0, stream>>>(
            off_, cnt_, src_, (const float4*)P0, P1, W4, R4, B4, out3,
            HS4, PS4, PC4, 3.0f, 1536, 8, 6, 1, 384);
        finalize_mean_kernel<<<(192 * 128 + 255) / 256, 256, 0, stream>>>(
            HS4, PS4, PC4, P1, (float4*)(P0 + 100000), 192);
    }
    // ---------- Layer 5: 192 nodes, CINF=128, COUT=128 -> hfin (no pool) ----------
    {
        ESORT(P3, e5, E5, 192);
        tsum_layer_kernel<128, 128, 2, 4, 0><<<192 / 8, 256, 0, stream>>>(
            off_, cnt_, src_, (const float4*)(P0 + 100000), P1, W5, R5, B5, hfin,
            nullptr, nullptr, nullptr, 1.5f, 192, 1, 1, 1, 1);
    }
#undef SPOOL2
#undef ESORT
#undef BSORT
#undef SCAN
#undef MSI
}